// Round 4
// baseline (340.063 us; speedup 1.0000x reference)
//
#include <hip/hip_runtime.h>
#include <hip/hip_bf16.h>
#include <cstdint>
#include <cstddef>
#include <type_traits>

#define D_MODEL 1024
#define NH      16
#define DH      64
#define LSEQ    2048
#define BATCH   4
#define NTOK    8192      // BATCH * LSEQ
#define K3      3072

typedef __attribute__((ext_vector_type(8))) short  short8;
typedef __attribute__((ext_vector_type(4))) float  floatx4;

__device__ __forceinline__ unsigned short f2bf_bits(float f) {
  __hip_bfloat16 h = __float2bfloat16(f);
  return __builtin_bit_cast(unsigned short, h);
}
__device__ __forceinline__ float bf2f(unsigned short u) {
  return __bfloat162float(__builtin_bit_cast(__hip_bfloat16, u));
}
__device__ __forceinline__ unsigned int pack_bf16(float lo, float hi) {
  return (unsigned int)f2bf_bits(lo) | ((unsigned int)f2bf_bits(hi) << 16);
}

__device__ __forceinline__ void gld_lds16(const void* g, void* l) {
  __builtin_amdgcn_global_load_lds(
      (const __attribute__((address_space(1))) void*)g,
      (__attribute__((address_space(3))) void*)l,
      16, 0, 0);
}

// ---------------------------------------------------------------- transpose+cast
// src: fp32 [R][C] -> dst: bf16 [C][R]
__global__ __launch_bounds__(256)
void transpose_cast(const float* __restrict__ src, __hip_bfloat16* __restrict__ dst,
                    int R, int C) {
  __shared__ float tile[32][33];
  const int c0 = blockIdx.x * 32, r0 = blockIdx.y * 32;
  const int x = threadIdx.x, y = threadIdx.y;   // 32 x 8
  #pragma unroll
  for (int j = 0; j < 32; j += 8)
    tile[y + j][x] = src[(size_t)(r0 + y + j) * C + c0 + x];
  __syncthreads();
  #pragma unroll
  for (int j = 0; j < 32; j += 8)
    dst[(size_t)(c0 + y + j) * R + r0 + x] = __float2bfloat16(tile[x][y + j]);
}

// ---------------------------------------------------------------- LayerNorm(x) -> bf16
__global__ __launch_bounds__(256)
void ln_kernel(const float* __restrict__ x, const float* __restrict__ w,
               const float* __restrict__ bb, __hip_bfloat16* __restrict__ h) {
  const int t = blockIdx.x, tid = threadIdx.x;
  const float4 v = reinterpret_cast<const float4*>(x + (size_t)t * D_MODEL)[tid];
  float s  = v.x + v.y + v.z + v.w;
  float ss = v.x*v.x + v.y*v.y + v.z*v.z + v.w*v.w;
  #pragma unroll
  for (int off = 32; off > 0; off >>= 1) {
    s  += __shfl_down(s, off);
    ss += __shfl_down(ss, off);
  }
  __shared__ float red[8];
  if ((tid & 63) == 0) { red[(tid >> 6) * 2] = s; red[(tid >> 6) * 2 + 1] = ss; }
  __syncthreads();
  s  = red[0] + red[2] + red[4] + red[6];
  ss = red[1] + red[3] + red[5] + red[7];
  const float mu  = s * (1.f / D_MODEL);
  const float var = ss * (1.f / D_MODEL) - mu * mu;
  const float rs  = rsqrtf(var + 1e-5f);
  const float4 wv = reinterpret_cast<const float4*>(w)[tid];
  const float4 bv = reinterpret_cast<const float4*>(bb)[tid];
  ushort4 o;
  o.x = f2bf_bits((v.x - mu) * rs * wv.x + bv.x);
  o.y = f2bf_bits((v.y - mu) * rs * wv.y + bv.y);
  o.z = f2bf_bits((v.z - mu) * rs * wv.z + bv.z);
  o.w = f2bf_bits((v.w - mu) * rs * wv.w + bv.w);
  reinterpret_cast<ushort4*>(h + (size_t)t * D_MODEL)[tid] = o;
}

// ---------------------------------------------------------------- bf16 GEMM, Bt layout
// A: bf16 [M][K] row-major, Bt: bf16 [N][K] (B transposed), C: OutT [M][N]
template <typename OutT>
__global__ __launch_bounds__(256, 2)
void gemm_bt(const __hip_bfloat16* __restrict__ A, const __hip_bfloat16* __restrict__ Bt,
             OutT* __restrict__ C, int M, int N, int K) {
  const int tid  = threadIdx.x;
  const int lane = tid & 63;
  const int wave = tid >> 6;
  const int bm = blockIdx.y * 128;
  const int bn = blockIdx.x * 128;
  const int wm = (wave & 1) * 64;
  const int wn = (wave >> 1) * 64;
  const int quad = lane >> 4;
  const int l16  = lane & 15;

  __shared__ __align__(16) __hip_bfloat16 As[128 * 32];
  __shared__ __align__(16) __hip_bfloat16 Bs[128 * 32];

  floatx4 acc[4][4];
  #pragma unroll
  for (int i = 0; i < 4; i++)
    #pragma unroll
    for (int j = 0; j < 4; j++) {
      floatx4 z = {0.f, 0.f, 0.f, 0.f};
      acc[i][j] = z;
    }

  const __hip_bfloat16* Ab = A  + (size_t)bm * K;
  const __hip_bfloat16* Bb = Bt + (size_t)bn * K;
  const int rowa = tid >> 2;
  const int kc   = (tid & 3) * 8;

  for (int k0 = 0; k0 < K; k0 += 32) {
    __syncthreads();
    gld_lds16(Ab + (size_t)rowa        * K + (k0 + kc), (char*)As + tid * 16);
    gld_lds16(Ab + (size_t)(rowa + 64) * K + (k0 + kc), (char*)As + 4096 + tid * 16);
    gld_lds16(Bb + (size_t)rowa        * K + (k0 + kc), (char*)Bs + tid * 16);
    gld_lds16(Bb + (size_t)(rowa + 64) * K + (k0 + kc), (char*)Bs + 4096 + tid * 16);
    __syncthreads();
    short8 af[4], bfr[4];
    #pragma unroll
    for (int i = 0; i < 4; i++)
      af[i] = *reinterpret_cast<const short8*>(As + (wm + i * 16 + l16) * 32 + quad * 8);
    #pragma unroll
    for (int j = 0; j < 4; j++)
      bfr[j] = *reinterpret_cast<const short8*>(Bs + (wn + j * 16 + l16) * 32 + quad * 8);
    #pragma unroll
    for (int i = 0; i < 4; i++)
      #pragma unroll
      for (int j = 0; j < 4; j++)
        acc[i][j] = __builtin_amdgcn_mfma_f32_16x16x32_bf16(af[i], bfr[j], acc[i][j], 0, 0, 0);
  }

  #pragma unroll
  for (int i = 0; i < 4; i++)
    #pragma unroll
    for (int j = 0; j < 4; j++) {
      const int row0 = bm + wm + i * 16 + quad * 4;
      const int col  = bn + wn + j * 16 + l16;
      #pragma unroll
      for (int r = 0; r < 4; r++) {
        if constexpr (std::is_same<OutT, __hip_bfloat16>::value)
          C[(size_t)(row0 + r) * N + col] = __float2bfloat16(acc[i][j][r]);
        else
          C[(size_t)(row0 + r) * N + col] = acc[i][j][r];
      }
    }
}

// ---------------------------------------------------------------- segment bounds
__global__ __launch_bounds__(256)
void seg_kernel(const int* __restrict__ sid, int* __restrict__ segstart,
                int* __restrict__ segend) {
  const int i = blockIdx.x * 256 + threadIdx.x;   // 0..8191
  const int b = i >> 11, l = i & 2047;
  const int* row = sid + (size_t)b * LSEQ;
  const int v = row[l];
  int lo = 0, hi = l;
  while (lo < hi) { int mid = (lo + hi) >> 1; if (row[mid] < v) lo = mid + 1; else hi = mid; }
  segstart[i] = lo;
  lo = l + 1; hi = LSEQ;
  while (lo < hi) { int mid = (lo + hi) >> 1; if (row[mid] <= v) lo = mid + 1; else hi = mid; }
  segend[i] = lo;
}

// ---------------------------------------------------------------- QK-LN + RoPE + scatter (bf16 in/out)
// qkv: bf16 [NTOK][3072]; outputs bf16 [B][H][L][DH]; Q pre-scaled by 1/8
__global__ __launch_bounds__(256)
void rope_kernel(const unsigned short* __restrict__ qkv, const float* __restrict__ qw,
                 const float* __restrict__ kw, unsigned short* __restrict__ qT,
                 unsigned short* __restrict__ kT, unsigned short* __restrict__ vN) {
  const int t = blockIdx.x, tid = threadIdx.x;
  const int b = t >> 11, l = t & 2047;
  const unsigned short* row = qkv + (size_t)t * K3;
  const ushort4 qu = reinterpret_cast<const ushort4*>(row)[tid];
  const ushort4 ku = reinterpret_cast<const ushort4*>(row + 1024)[tid];
  const ushort4 vu = reinterpret_cast<const ushort4*>(row + 2048)[tid];
  const float4 q4 = make_float4(bf2f(qu.x), bf2f(qu.y), bf2f(qu.z), bf2f(qu.w));
  const float4 k4 = make_float4(bf2f(ku.x), bf2f(ku.y), bf2f(ku.z), bf2f(ku.w));
  float qs  = q4.x + q4.y + q4.z + q4.w;
  float qss = q4.x*q4.x + q4.y*q4.y + q4.z*q4.z + q4.w*q4.w;
  float ks  = k4.x + k4.y + k4.z + k4.w;
  float kss = k4.x*k4.x + k4.y*k4.y + k4.z*k4.z + k4.w*k4.w;
  #pragma unroll
  for (int off = 32; off > 0; off >>= 1) {
    qs  += __shfl_down(qs, off);  qss += __shfl_down(qss, off);
    ks  += __shfl_down(ks, off);  kss += __shfl_down(kss, off);
  }
  __shared__ float red[16];
  const int w = tid >> 6;
  if ((tid & 63) == 0) {
    red[w*4] = qs; red[w*4+1] = qss; red[w*4+2] = ks; red[w*4+3] = kss;
  }
  __syncthreads();
  qs  = red[0] + red[4] + red[8]  + red[12];
  qss = red[1] + red[5] + red[9]  + red[13];
  ks  = red[2] + red[6] + red[10] + red[14];
  kss = red[3] + red[7] + red[11] + red[15];
  const float qmu = qs * (1.f/1024), qvar = qss * (1.f/1024) - qmu*qmu;
  const float qrs = rsqrtf(qvar + 1e-5f);
  const float kmu = ks * (1.f/1024), kvar = kss * (1.f/1024) - kmu*kmu;
  const float krs = rsqrtf(kvar + 1e-5f);

  __shared__ float qn[1024];
  __shared__ float kn[1024];
  const float4 qwv = reinterpret_cast<const float4*>(qw)[tid];
  const float4 kwv = reinterpret_cast<const float4*>(kw)[tid];
  const int d = tid * 4;
  qn[d+0] = (q4.x - qmu) * qrs * qwv.x;
  qn[d+1] = (q4.y - qmu) * qrs * qwv.y;
  qn[d+2] = (q4.z - qmu) * qrs * qwv.z;
  qn[d+3] = (q4.w - qmu) * qrs * qwv.w;
  kn[d+0] = (k4.x - kmu) * krs * kwv.x;
  kn[d+1] = (k4.y - kmu) * krs * kwv.y;
  kn[d+2] = (k4.z - kmu) * krs * kwv.z;
  kn[d+3] = (k4.w - kmu) * krs * kwv.w;
  __syncthreads();

  const int hh = d >> 6, dh = d & 63;
  float oq[4], ok[4];
  #pragma unroll
  for (int i = 0; i < 4; i++) {
    const int dd = dh + i;
    const int j = dd & 31;
    const float th = (float)l * __expf(-(float)j * 0.28782313662425575f); // ln(1e4)/32
    const float cs = cosf(th), sn = sinf(th);
    const float qp = (dd < 32) ? -qn[d + i + 32] : qn[d + i - 32];
    const float kp = (dd < 32) ? -kn[d + i + 32] : kn[d + i - 32];
    oq[i] = (qn[d + i] * cs + qp * sn) * 0.125f;   // fold 1/sqrt(Dh) into Q
    ok[i] = kn[d + i] * cs + kp * sn;
  }
  const size_t ob = ((size_t)(b * NH + hh) * LSEQ + l) * DH + dh;
  ushort4 pq, pk, pv;
  pq.x = f2bf_bits(oq[0]); pq.y = f2bf_bits(oq[1]); pq.z = f2bf_bits(oq[2]); pq.w = f2bf_bits(oq[3]);
  pk.x = f2bf_bits(ok[0]); pk.y = f2bf_bits(ok[1]); pk.z = f2bf_bits(ok[2]); pk.w = f2bf_bits(ok[3]);
  pv = vu;
  *reinterpret_cast<ushort4*>(qT + ob) = pq;
  *reinterpret_cast<ushort4*>(kT + ob) = pk;
  *reinterpret_cast<ushort4*>(vN + ob) = pv;
}

// ---------------------------------------------------------------- V transpose per (b,h)
// vN: bf16 [BH][L][DH] -> vT: bf16 [BH][DH][L]
__global__ __launch_bounds__(256)
void vtrans(const unsigned short* __restrict__ vN, unsigned short* __restrict__ vT) {
  __shared__ __align__(16) unsigned short T[64 * 72];
  const int bh = blockIdx.y;
  const int l0 = blockIdx.x * 64;
  const int tid = threadIdx.x;
  #pragma unroll
  for (int it = 0; it < 2; it++) {
    const int cid = tid + it * 256;
    const int r = cid >> 3, c = (cid & 7) * 8;
    *reinterpret_cast<short8*>(T + r * 72 + c) =
        *reinterpret_cast<const short8*>(vN + ((size_t)bh * LSEQ + l0 + r) * DH + c);
  }
  __syncthreads();
  #pragma unroll
  for (int it = 0; it < 2; it++) {
    const int cid = tid + it * 256;
    const int dh = cid >> 3, c = (cid & 7) * 8;
    short8 o;
    #pragma unroll
    for (int e = 0; e < 8; e++) o[e] = (short)T[(c + e) * 72 + dh];
    *reinterpret_cast<short8*>(vT + ((size_t)bh * DH + dh) * LSEQ + l0 + c) = o;
  }
}

// ---------------------------------------------------------------- MFMA flash attention, S^T form
// qT,kT: bf16 [BH][L][DH] (Q pre-scaled); vT: bf16 [BH][DH][L]; ctx: bf16 [B][L][H*DH]
// Each wave: 16 queries (one per lane col), k-loop over its own segment span.
// No __syncthreads in the loop; K/V/Q fragments direct from global (L1-shared).
__global__ __launch_bounds__(256)
void attn_mfma(const unsigned short* __restrict__ qT, const unsigned short* __restrict__ kT,
               const unsigned short* __restrict__ vT, const int* __restrict__ segs,
               const int* __restrict__ sege, unsigned short* __restrict__ ctx) {
  const int tid  = threadIdx.x;
  const int lane = tid & 63, w = tid >> 6;
  const int quad = lane >> 4, l16 = lane & 15;
  const int h = blockIdx.y, b = blockIdx.z;
  const int qy = blockIdx.x * 64 + w * 16 + l16;   // this lane's query (same across quads)
  const size_t bh = (size_t)(b * NH + h);
  const unsigned short* Kg = kT + bh * LSEQ * DH;
  const unsigned short* Vg = vT + bh * DH * LSEQ;

  // per-wave P staging: [16 q][72 k] bf16  (ds_write_b64 from C-regs, ds_read_b128 as B-frag)
  __shared__ __align__(16) unsigned short Ps[4][16 * 72];

  // Q as B-operand: B[k=dh][n=q]; lane loads row qy, dh chunks quad*8, 32+quad*8
  const unsigned short* Qrow = qT + (bh * LSEQ + qy) * DH;
  const short8 qf0 = *reinterpret_cast<const short8*>(Qrow + quad * 8);
  const short8 qf1 = *reinterpret_cast<const short8*>(Qrow + 32 + quad * 8);

  const int st = segs[b * LSEQ + qy];
  const int en = sege[b * LSEQ + qy];
  const unsigned span = (unsigned)(en - st);
  const int kmin = __shfl(st, 0) & ~7;   // 8-aligned so V-vector loads stay element-aligned
  const int kmax = __shfl(en, 15);

  floatx4 acc[4];
  #pragma unroll
  for (int dt = 0; dt < 4; dt++) { floatx4 z = {0.f,0.f,0.f,0.f}; acc[dt] = z; }
  float m = -1e30f, lsum = 0.f;

  for (int kk = kmin; kk < kmax; kk += 64) {
    // S^T = K Q^T : 4 key-subtiles of 16, C layout row=key(quad*4+reg), col=q(l16)
    floatx4 sc[4];
    #pragma unroll
    for (int t = 0; t < 4; t++) {
      int krow = kk + t * 16 + l16; if (krow > LSEQ - 1) krow = LSEQ - 1;
      const unsigned short* Kr = Kg + (size_t)krow * DH;
      const short8 kf0 = *reinterpret_cast<const short8*>(Kr + quad * 8);
      const short8 kf1 = *reinterpret_cast<const short8*>(Kr + 32 + quad * 8);
      floatx4 z = {0.f,0.f,0.f,0.f};
      sc[t] = __builtin_amdgcn_mfma_f32_16x16x32_bf16(kf0, qf0, z, 0, 0, 0);
      sc[t] = __builtin_amdgcn_mfma_f32_16x16x32_bf16(kf1, qf1, sc[t], 0, 0, 0);
    }

    // mask + in-lane max over 16 keys, then reduce across quads (2 shfls)
    float vm = -1e30f;
    #pragma unroll
    for (int t = 0; t < 4; t++) {
      const int k0 = kk + t * 16 + quad * 4;
      #pragma unroll
      for (int r = 0; r < 4; r++) {
        const bool ok = (unsigned)(k0 + r - st) < span;
        sc[t][r] = ok ? sc[t][r] : -1e30f;
        vm = fmaxf(vm, sc[t][r]);
      }
    }
    vm = fmaxf(vm, __shfl_xor(vm, 16));
    vm = fmaxf(vm, __shfl_xor(vm, 32));
    const float mn = fmaxf(m, vm);
    const float alpha = __expf(m - mn);
    m = mn;

    // exp + pack 4 consecutive keys -> one b64 LDS write per subtile
    float rs = 0.f;
    #pragma unroll
    for (int t = 0; t < 4; t++) {
      float p0 = (sc[t][0] > -1e29f) ? __expf(sc[t][0] - mn) : 0.f;
      float p1 = (sc[t][1] > -1e29f) ? __expf(sc[t][1] - mn) : 0.f;
      float p2 = (sc[t][2] > -1e29f) ? __expf(sc[t][2] - mn) : 0.f;
      float p3 = (sc[t][3] > -1e29f) ? __expf(sc[t][3] - mn) : 0.f;
      rs += (p0 + p1) + (p2 + p3);
      uint2 pk;
      pk.x = pack_bf16(p0, p1);
      pk.y = pack_bf16(p2, p3);
      *reinterpret_cast<uint2*>(&Ps[w][l16 * 72 + t * 16 + quad * 4]) = pk;
    }
    rs += __shfl_xor(rs, 16);
    rs += __shfl_xor(rs, 32);
    lsum = lsum * alpha + rs;

    // read P back as B-operand rows [q=l16][k-chunk] (intra-wave, no barrier)
    const short8 pf0 = *reinterpret_cast<const short8*>(&Ps[w][l16 * 72 + quad * 8]);
    const short8 pf1 = *reinterpret_cast<const short8*>(&Ps[w][l16 * 72 + 32 + quad * 8]);

    // O^T = alpha*O^T + V^T P^T : A = V^T rows d, direct from global
    #pragma unroll
    for (int dt = 0; dt < 4; dt++) {
      #pragma unroll
      for (int r = 0; r < 4; r++) acc[dt][r] *= alpha;
      const unsigned short* Vr = Vg + (size_t)(dt * 16 + l16) * LSEQ;
      int c0 = kk + quad * 8;      if (c0 > LSEQ - 8) c0 = LSEQ - 8;
      int c1 = kk + 32 + quad * 8; if (c1 > LSEQ - 8) c1 = LSEQ - 8;
      const short8 vf0 = *reinterpret_cast<const short8*>(Vr + c0);
      const short8 vf1 = *reinterpret_cast<const short8*>(Vr + c1);
      acc[dt] = __builtin_amdgcn_mfma_f32_16x16x32_bf16(vf0, pf0, acc[dt], 0, 0, 0);
      acc[dt] = __builtin_amdgcn_mfma_f32_16x16x32_bf16(vf1, pf1, acc[dt], 0, 0, 0);
    }
  }

  // epilogue: O^T regs hold d = dt*16+quad*4+r for query l16 -> 4 consecutive d = 8B stores
  const float inv = (lsum > 0.f) ? 1.f / lsum : 0.f;
  unsigned short* orow = ctx + ((size_t)(b * LSEQ + qy)) * D_MODEL + h * DH;
  #pragma unroll
  for (int dt = 0; dt < 4; dt++) {
    uint2 o;
    o.x = pack_bf16(acc[dt][0] * inv, acc[dt][1] * inv);
    o.y = pack_bf16(acc[dt][2] * inv, acc[dt][3] * inv);
    *reinterpret_cast<uint2*>(orow + dt * 16 + quad * 4) = o;
  }
}

// ---------------------------------------------------------------- launch
extern "C" void kernel_launch(void* const* d_in, const int* in_sizes, int n_in,
                              void* d_out, int out_size, void* d_ws, size_t ws_size,
                              hipStream_t stream) {
  const float* x      = (const float*)d_in[0];
  const int*   sid    = (const int*)d_in[1];
  const float* ln_w   = (const float*)d_in[2];
  const float* ln_b   = (const float*)d_in[3];
  const float* w_qkv  = (const float*)d_in[4];
  const float* q_ln_w = (const float*)d_in[5];
  const float* k_ln_w = (const float*)d_in[6];
  const float* w_out  = (const float*)d_in[7];
  float* out = (float*)d_out;
  char* ws = (char*)d_ws;

  constexpr size_t OFF_WQKVT = 0;                        //  6,291,456
  constexpr size_t OFF_WOUTT = 6291456;                  //  2,097,152
  constexpr size_t OFF_H     = 8388608;                  // 16,777,216
  constexpr size_t OFF_QKV   = 25165824;                 // 50,331,648 (bf16 now)
  constexpr size_t OFF_QT    = 75497472;                 // 16,777,216
  constexpr size_t OFF_KT    = 92274688;                 // 16,777,216
  constexpr size_t OFF_VN    = 109051904;                // 16,777,216
  constexpr size_t OFF_VT    = 125829120;                // 16,777,216
  constexpr size_t OFF_CTX   = 142606336;                // 16,777,216
  constexpr size_t OFF_SEGS  = 159383552;                // 32,768
  constexpr size_t OFF_SEGE  = 159416320;                // 32,768

  __hip_bfloat16* wqkvT = (__hip_bfloat16*)(ws + OFF_WQKVT);
  __hip_bfloat16* woutT = (__hip_bfloat16*)(ws + OFF_WOUTT);
  __hip_bfloat16* hbuf  = (__hip_bfloat16*)(ws + OFF_H);
  __hip_bfloat16* qkvb  = (__hip_bfloat16*)(ws + OFF_QKV);
  unsigned short* qTb   = (unsigned short*)(ws + OFF_QT);
  unsigned short* kTb   = (unsigned short*)(ws + OFF_KT);
  unsigned short* vNb   = (unsigned short*)(ws + OFF_VN);
  unsigned short* vTb   = (unsigned short*)(ws + OFF_VT);
  unsigned short* ctx   = (unsigned short*)(ws + OFF_CTX);
  int*            segst = (int*)(ws + OFF_SEGS);
  int*            segen = (int*)(ws + OFF_SEGE);

  transpose_cast<<<dim3(96, 32), dim3(32, 8), 0, stream>>>(w_qkv, wqkvT, 1024, 3072);
  transpose_cast<<<dim3(32, 32), dim3(32, 8), 0, stream>>>(w_out, woutT, 1024, 1024);
  ln_kernel<<<NTOK, 256, 0, stream>>>(x, ln_w, ln_b, hbuf);
  gemm_bt<__hip_bfloat16><<<dim3(K3 / 128, NTOK / 128), 256, 0, stream>>>(
      hbuf, wqkvT, qkvb, NTOK, K3, 1024);
  seg_kernel<<<NTOK / 256, 256, 0, stream>>>(sid, segst, segen);
  rope_kernel<<<NTOK, 256, 0, stream>>>((const unsigned short*)qkvb, q_ln_w, k_ln_w,
                                        qTb, kTb, vNb);
  vtrans<<<dim3(LSEQ / 64, BATCH * NH), 256, 0, stream>>>(vNb, vTb);
  attn_mfma<<<dim3(LSEQ / 64, NH, BATCH), 256, 0, stream>>>(qTb, kTb, vTb, segst, segen, ctx);
  gemm_bt<float><<<dim3(D_MODEL / 128, NTOK / 128), 256, 0, stream>>>(
      (const __hip_bfloat16*)ctx, woutT, out, NTOK, D_MODEL, 1024);
}

// Round 5
// 287.448 us; speedup vs baseline: 1.1830x; 1.1830x over previous
//
#include <hip/hip_runtime.h>
#include <hip/hip_bf16.h>
#include <cstdint>
#include <cstddef>
#include <type_traits>

#define D_MODEL 1024
#define NH      16
#define DH      64
#define LSEQ    2048
#define BATCH   4
#define NTOK    8192      // BATCH * LSEQ
#define K3      3072

typedef __attribute__((ext_vector_type(8))) short  short8;
typedef __attribute__((ext_vector_type(4))) float  floatx4;

__device__ __forceinline__ unsigned short f2bf_bits(float f) {
  __hip_bfloat16 h = __float2bfloat16(f);
  return __builtin_bit_cast(unsigned short, h);
}
__device__ __forceinline__ float bf2f(unsigned short u) {
  return __bfloat162float(__builtin_bit_cast(__hip_bfloat16, u));
}
__device__ __forceinline__ unsigned int pack_bf16(float lo, float hi) {
  return (unsigned int)f2bf_bits(lo) | ((unsigned int)f2bf_bits(hi) << 16);
}

__device__ __forceinline__ void gld_lds16(const void* g, void* l) {
  __builtin_amdgcn_global_load_lds(
      (const __attribute__((address_space(1))) void*)g,
      (__attribute__((address_space(3))) void*)l,
      16, 0, 0);
}

// ---------------------------------------------------------------- transpose+cast
// src: fp32 [R][C] -> dst: bf16 [C][R]
__global__ __launch_bounds__(256)
void transpose_cast(const float* __restrict__ src, __hip_bfloat16* __restrict__ dst,
                    int R, int C) {
  __shared__ float tile[32][33];
  const int c0 = blockIdx.x * 32, r0 = blockIdx.y * 32;
  const int x = threadIdx.x, y = threadIdx.y;   // 32 x 8
  #pragma unroll
  for (int j = 0; j < 32; j += 8)
    tile[y + j][x] = src[(size_t)(r0 + y + j) * C + c0 + x];
  __syncthreads();
  #pragma unroll
  for (int j = 0; j < 32; j += 8)
    dst[(size_t)(c0 + y + j) * R + r0 + x] = __float2bfloat16(tile[x][y + j]);
}

// ---------------------------------------------------------------- LayerNorm(x) -> bf16
__global__ __launch_bounds__(256)
void ln_kernel(const float* __restrict__ x, const float* __restrict__ w,
               const float* __restrict__ bb, __hip_bfloat16* __restrict__ h) {
  const int t = blockIdx.x, tid = threadIdx.x;
  const float4 v = reinterpret_cast<const float4*>(x + (size_t)t * D_MODEL)[tid];
  float s  = v.x + v.y + v.z + v.w;
  float ss = v.x*v.x + v.y*v.y + v.z*v.z + v.w*v.w;
  #pragma unroll
  for (int off = 32; off > 0; off >>= 1) {
    s  += __shfl_down(s, off);
    ss += __shfl_down(ss, off);
  }
  __shared__ float red[8];
  if ((tid & 63) == 0) { red[(tid >> 6) * 2] = s; red[(tid >> 6) * 2 + 1] = ss; }
  __syncthreads();
  s  = red[0] + red[2] + red[4] + red[6];
  ss = red[1] + red[3] + red[5] + red[7];
  const float mu  = s * (1.f / D_MODEL);
  const float var = ss * (1.f / D_MODEL) - mu * mu;
  const float rs  = rsqrtf(var + 1e-5f);
  const float4 wv = reinterpret_cast<const float4*>(w)[tid];
  const float4 bv = reinterpret_cast<const float4*>(bb)[tid];
  ushort4 o;
  o.x = f2bf_bits((v.x - mu) * rs * wv.x + bv.x);
  o.y = f2bf_bits((v.y - mu) * rs * wv.y + bv.y);
  o.z = f2bf_bits((v.z - mu) * rs * wv.z + bv.z);
  o.w = f2bf_bits((v.w - mu) * rs * wv.w + bv.w);
  reinterpret_cast<ushort4*>(h + (size_t)t * D_MODEL)[tid] = o;
}

// ---------------------------------------------------------------- bf16 GEMM, Bt layout
// A: bf16 [M][K] row-major, Bt: bf16 [N][K] (B transposed), C: OutT [M][N]
template <typename OutT>
__global__ __launch_bounds__(256, 2)
void gemm_bt(const __hip_bfloat16* __restrict__ A, const __hip_bfloat16* __restrict__ Bt,
             OutT* __restrict__ C, int M, int N, int K) {
  const int tid  = threadIdx.x;
  const int lane = tid & 63;
  const int wave = tid >> 6;
  const int bm = blockIdx.y * 128;
  const int bn = blockIdx.x * 128;
  const int wm = (wave & 1) * 64;
  const int wn = (wave >> 1) * 64;
  const int quad = lane >> 4;
  const int l16  = lane & 15;

  __shared__ __align__(16) __hip_bfloat16 As[128 * 32];
  __shared__ __align__(16) __hip_bfloat16 Bs[128 * 32];

  floatx4 acc[4][4];
  #pragma unroll
  for (int i = 0; i < 4; i++)
    #pragma unroll
    for (int j = 0; j < 4; j++) {
      floatx4 z = {0.f, 0.f, 0.f, 0.f};
      acc[i][j] = z;
    }

  const __hip_bfloat16* Ab = A  + (size_t)bm * K;
  const __hip_bfloat16* Bb = Bt + (size_t)bn * K;
  const int rowa = tid >> 2;
  const int kc   = (tid & 3) * 8;

  for (int k0 = 0; k0 < K; k0 += 32) {
    __syncthreads();
    gld_lds16(Ab + (size_t)rowa        * K + (k0 + kc), (char*)As + tid * 16);
    gld_lds16(Ab + (size_t)(rowa + 64) * K + (k0 + kc), (char*)As + 4096 + tid * 16);
    gld_lds16(Bb + (size_t)rowa        * K + (k0 + kc), (char*)Bs + tid * 16);
    gld_lds16(Bb + (size_t)(rowa + 64) * K + (k0 + kc), (char*)Bs + 4096 + tid * 16);
    __syncthreads();
    short8 af[4], bfr[4];
    #pragma unroll
    for (int i = 0; i < 4; i++)
      af[i] = *reinterpret_cast<const short8*>(As + (wm + i * 16 + l16) * 32 + quad * 8);
    #pragma unroll
    for (int j = 0; j < 4; j++)
      bfr[j] = *reinterpret_cast<const short8*>(Bs + (wn + j * 16 + l16) * 32 + quad * 8);
    #pragma unroll
    for (int i = 0; i < 4; i++)
      #pragma unroll
      for (int j = 0; j < 4; j++)
        acc[i][j] = __builtin_amdgcn_mfma_f32_16x16x32_bf16(af[i], bfr[j], acc[i][j], 0, 0, 0);
  }

  #pragma unroll
  for (int i = 0; i < 4; i++)
    #pragma unroll
    for (int j = 0; j < 4; j++) {
      const int row0 = bm + wm + i * 16 + quad * 4;
      const int col  = bn + wn + j * 16 + l16;
      #pragma unroll
      for (int r = 0; r < 4; r++) {
        if constexpr (std::is_same<OutT, __hip_bfloat16>::value)
          C[(size_t)(row0 + r) * N + col] = __float2bfloat16(acc[i][j][r]);
        else
          C[(size_t)(row0 + r) * N + col] = acc[i][j][r];
      }
    }
}

// ---------------------------------------------------------------- segment bounds
__global__ __launch_bounds__(256)
void seg_kernel(const int* __restrict__ sid, int* __restrict__ segstart,
                int* __restrict__ segend) {
  const int i = blockIdx.x * 256 + threadIdx.x;   // 0..8191
  const int b = i >> 11, l = i & 2047;
  const int* row = sid + (size_t)b * LSEQ;
  const int v = row[l];
  int lo = 0, hi = l;
  while (lo < hi) { int mid = (lo + hi) >> 1; if (row[mid] < v) lo = mid + 1; else hi = mid; }
  segstart[i] = lo;
  lo = l + 1; hi = LSEQ;
  while (lo < hi) { int mid = (lo + hi) >> 1; if (row[mid] <= v) lo = mid + 1; else hi = mid; }
  segend[i] = lo;
}

// ---------------------------------------------------------------- QK-LN + RoPE + scatter (bf16 in/out)
// qkv: bf16 [NTOK][3072]; outputs bf16 [B][H][L][DH]; Q pre-scaled by 1/8
__global__ __launch_bounds__(256)
void rope_kernel(const unsigned short* __restrict__ qkv, const float* __restrict__ qw,
                 const float* __restrict__ kw, unsigned short* __restrict__ qT,
                 unsigned short* __restrict__ kT, unsigned short* __restrict__ vN) {
  const int t = blockIdx.x, tid = threadIdx.x;
  const int b = t >> 11, l = t & 2047;
  const unsigned short* row = qkv + (size_t)t * K3;
  const ushort4 qu = reinterpret_cast<const ushort4*>(row)[tid];
  const ushort4 ku = reinterpret_cast<const ushort4*>(row + 1024)[tid];
  const ushort4 vu = reinterpret_cast<const ushort4*>(row + 2048)[tid];
  const float4 q4 = make_float4(bf2f(qu.x), bf2f(qu.y), bf2f(qu.z), bf2f(qu.w));
  const float4 k4 = make_float4(bf2f(ku.x), bf2f(ku.y), bf2f(ku.z), bf2f(ku.w));
  float qs  = q4.x + q4.y + q4.z + q4.w;
  float qss = q4.x*q4.x + q4.y*q4.y + q4.z*q4.z + q4.w*q4.w;
  float ks  = k4.x + k4.y + k4.z + k4.w;
  float kss = k4.x*k4.x + k4.y*k4.y + k4.z*k4.z + k4.w*k4.w;
  #pragma unroll
  for (int off = 32; off > 0; off >>= 1) {
    qs  += __shfl_down(qs, off);  qss += __shfl_down(qss, off);
    ks  += __shfl_down(ks, off);  kss += __shfl_down(kss, off);
  }
  __shared__ float red[16];
  const int w = tid >> 6;
  if ((tid & 63) == 0) {
    red[w*4] = qs; red[w*4+1] = qss; red[w*4+2] = ks; red[w*4+3] = kss;
  }
  __syncthreads();
  qs  = red[0] + red[4] + red[8]  + red[12];
  qss = red[1] + red[5] + red[9]  + red[13];
  ks  = red[2] + red[6] + red[10] + red[14];
  kss = red[3] + red[7] + red[11] + red[15];
  const float qmu = qs * (1.f/1024), qvar = qss * (1.f/1024) - qmu*qmu;
  const float qrs = rsqrtf(qvar + 1e-5f);
  const float kmu = ks * (1.f/1024), kvar = kss * (1.f/1024) - kmu*kmu;
  const float krs = rsqrtf(kvar + 1e-5f);

  __shared__ float qn[1024];
  __shared__ float kn[1024];
  const float4 qwv = reinterpret_cast<const float4*>(qw)[tid];
  const float4 kwv = reinterpret_cast<const float4*>(kw)[tid];
  const int d = tid * 4;
  qn[d+0] = (q4.x - qmu) * qrs * qwv.x;
  qn[d+1] = (q4.y - qmu) * qrs * qwv.y;
  qn[d+2] = (q4.z - qmu) * qrs * qwv.z;
  qn[d+3] = (q4.w - qmu) * qrs * qwv.w;
  kn[d+0] = (k4.x - kmu) * krs * kwv.x;
  kn[d+1] = (k4.y - kmu) * krs * kwv.y;
  kn[d+2] = (k4.z - kmu) * krs * kwv.z;
  kn[d+3] = (k4.w - kmu) * krs * kwv.w;
  __syncthreads();

  const int hh = d >> 6, dh = d & 63;
  float oq[4], ok[4];
  #pragma unroll
  for (int i = 0; i < 4; i++) {
    const int dd = dh + i;
    const int j = dd & 31;
    const float th = (float)l * __expf(-(float)j * 0.28782313662425575f); // ln(1e4)/32
    const float cs = cosf(th), sn = sinf(th);
    const float qp = (dd < 32) ? -qn[d + i + 32] : qn[d + i - 32];
    const float kp = (dd < 32) ? -kn[d + i + 32] : kn[d + i - 32];
    oq[i] = (qn[d + i] * cs + qp * sn) * 0.125f;   // fold 1/sqrt(Dh) into Q
    ok[i] = kn[d + i] * cs + kp * sn;
  }
  const size_t ob = ((size_t)(b * NH + hh) * LSEQ + l) * DH + dh;
  ushort4 pq, pk, pv;
  pq.x = f2bf_bits(oq[0]); pq.y = f2bf_bits(oq[1]); pq.z = f2bf_bits(oq[2]); pq.w = f2bf_bits(oq[3]);
  pk.x = f2bf_bits(ok[0]); pk.y = f2bf_bits(ok[1]); pk.z = f2bf_bits(ok[2]); pk.w = f2bf_bits(ok[3]);
  pv = vu;
  *reinterpret_cast<ushort4*>(qT + ob) = pq;
  *reinterpret_cast<ushort4*>(kT + ob) = pk;
  *reinterpret_cast<ushort4*>(vN + ob) = pv;
}

// ---------------------------------------------------------------- V transpose per (b,h)
// vN: bf16 [BH][L][DH] -> vT: bf16 [BH][DH][L]
__global__ __launch_bounds__(256)
void vtrans(const unsigned short* __restrict__ vN, unsigned short* __restrict__ vT) {
  __shared__ __align__(16) unsigned short T[64 * 72];
  const int bh = blockIdx.y;
  const int l0 = blockIdx.x * 64;
  const int tid = threadIdx.x;
  #pragma unroll
  for (int it = 0; it < 2; it++) {
    const int cid = tid + it * 256;
    const int r = cid >> 3, c = (cid & 7) * 8;
    *reinterpret_cast<short8*>(T + r * 72 + c) =
        *reinterpret_cast<const short8*>(vN + ((size_t)bh * LSEQ + l0 + r) * DH + c);
  }
  __syncthreads();
  #pragma unroll
  for (int it = 0; it < 2; it++) {
    const int cid = tid + it * 256;
    const int dh = cid >> 3, c = (cid & 7) * 8;
    short8 o;
    #pragma unroll
    for (int e = 0; e < 8; e++) o[e] = (short)T[(c + e) * 72 + dh];
    *reinterpret_cast<short8*>(vT + ((size_t)bh * DH + dh) * LSEQ + l0 + c) = o;
  }
}

// ---------------------------------------------------------------- MFMA flash attention
// S^T-form softmax (round-2) + cooperative LDS staging of K/V tiles (round-1).
// qT,kT: bf16 [BH][L][DH] (Q pre-scaled); vT: bf16 [BH][DH][L]; ctx: bf16 [B][L][H*DH]
__global__ __launch_bounds__(256)
void attn_mfma(const unsigned short* __restrict__ qT, const unsigned short* __restrict__ kT,
               const unsigned short* __restrict__ vT, const int* __restrict__ segs,
               const int* __restrict__ sege, unsigned short* __restrict__ ctx) {
  const int tid  = threadIdx.x;
  const int lane = tid & 63, w = tid >> 6;
  const int quad = lane >> 4, l16 = lane & 15;
  const int qbase = blockIdx.x * 64;
  const int h = blockIdx.y, b = blockIdx.z;
  const int qy = qbase + w * 16 + l16;            // this lane's query (same across quads)
  const size_t bh = (size_t)(b * NH + h);
  const unsigned short* Kg = kT + bh * LSEQ * DH;
  const unsigned short* Vg = vT + bh * DH * LSEQ;

  __shared__ __align__(16) unsigned short Ks[64 * 72];   // K rows [key][dh]
  __shared__ __align__(16) unsigned short Vs[64 * 72];   // V^T rows [dh][key]
  __shared__ __align__(16) unsigned short Ps[4][16 * 72];

  // Q as B-operand: B[k=dh][n=q]; one-time direct load
  const unsigned short* Qrow = qT + (bh * LSEQ + qy) * DH;
  const short8 qf0 = *reinterpret_cast<const short8*>(Qrow + quad * 8);
  const short8 qf1 = *reinterpret_cast<const short8*>(Qrow + 32 + quad * 8);

  const int st = segs[b * LSEQ + qy];
  const int en = sege[b * LSEQ + qy];
  const unsigned span = (unsigned)(en - st);
  // block range (sequence_ids sorted => first query's start is min, last's end is max)
  const int kmin = segs[b * LSEQ + qbase] & ~63;
  const int kmax = sege[b * LSEQ + qbase + 63];
  // this wave's range (for skipping tiles)
  const int wmin = segs[b * LSEQ + qbase + w * 16];
  const int wmax = sege[b * LSEQ + qbase + w * 16 + 15];

  floatx4 acc[4];
  #pragma unroll
  for (int dt = 0; dt < 4; dt++) { floatx4 z = {0.f,0.f,0.f,0.f}; acc[dt] = z; }
  float m = -1e30f, lsum = 0.f;

  const int r_ = tid >> 3, c_ = (tid & 7) * 8;   // staging coords (row 0..31 per iter half)

  for (int kk = kmin; kk < kmax; kk += 64) {
    __syncthreads();
    #pragma unroll
    for (int it = 0; it < 2; it++) {
      const int r = r_ + it * 32;
      *reinterpret_cast<short8*>(Ks + r * 72 + c_) =
          *reinterpret_cast<const short8*>(Kg + (size_t)(kk + r) * DH + c_);
      *reinterpret_cast<short8*>(Vs + r * 72 + c_) =
          *reinterpret_cast<const short8*>(Vg + (size_t)r * LSEQ + kk + c_);
    }
    __syncthreads();

    if (kk + 64 <= wmin || kk >= wmax) continue;   // tile fully outside this wave's span

    // S^T = K Q^T : 4 key-subtiles of 16; C layout row=key(quad*4+reg), col=q(l16)
    floatx4 sc[4];
    #pragma unroll
    for (int t = 0; t < 4; t++) {
      const short8 kf0 = *reinterpret_cast<const short8*>(Ks + (t * 16 + l16) * 72 + quad * 8);
      const short8 kf1 = *reinterpret_cast<const short8*>(Ks + (t * 16 + l16) * 72 + 32 + quad * 8);
      floatx4 z = {0.f,0.f,0.f,0.f};
      sc[t] = __builtin_amdgcn_mfma_f32_16x16x32_bf16(kf0, qf0, z, 0, 0, 0);
      sc[t] = __builtin_amdgcn_mfma_f32_16x16x32_bf16(kf1, qf1, sc[t], 0, 0, 0);
    }

    // mask + in-lane max over 16 keys, then 2 shfls across quads
    float vm = -1e30f;
    #pragma unroll
    for (int t = 0; t < 4; t++) {
      const int k0 = kk + t * 16 + quad * 4;
      #pragma unroll
      for (int r = 0; r < 4; r++) {
        const bool ok = (unsigned)(k0 + r - st) < span;
        sc[t][r] = ok ? sc[t][r] : -1e30f;
        vm = fmaxf(vm, sc[t][r]);
      }
    }
    vm = fmaxf(vm, __shfl_xor(vm, 16));
    vm = fmaxf(vm, __shfl_xor(vm, 32));
    const float mn = fmaxf(m, vm);
    const float alpha = __expf(m - mn);
    m = mn;

    // exp + pack 4 consecutive keys -> one b64 LDS write per subtile
    float rs = 0.f;
    #pragma unroll
    for (int t = 0; t < 4; t++) {
      float p0 = (sc[t][0] > -1e29f) ? __expf(sc[t][0] - mn) : 0.f;
      float p1 = (sc[t][1] > -1e29f) ? __expf(sc[t][1] - mn) : 0.f;
      float p2 = (sc[t][2] > -1e29f) ? __expf(sc[t][2] - mn) : 0.f;
      float p3 = (sc[t][3] > -1e29f) ? __expf(sc[t][3] - mn) : 0.f;
      rs += (p0 + p1) + (p2 + p3);
      uint2 pk;
      pk.x = pack_bf16(p0, p1);
      pk.y = pack_bf16(p2, p3);
      *reinterpret_cast<uint2*>(&Ps[w][l16 * 72 + t * 16 + quad * 4]) = pk;
    }
    rs += __shfl_xor(rs, 16);
    rs += __shfl_xor(rs, 32);
    lsum = lsum * alpha + rs;

    // read P back as B-operand rows [q=l16][k-chunk] (intra-wave, no barrier)
    const short8 pf0 = *reinterpret_cast<const short8*>(&Ps[w][l16 * 72 + quad * 8]);
    const short8 pf1 = *reinterpret_cast<const short8*>(&Ps[w][l16 * 72 + 32 + quad * 8]);

    // O^T = alpha*O^T + V^T P^T : A = V^T rows (from LDS)
    #pragma unroll
    for (int dt = 0; dt < 4; dt++) {
      #pragma unroll
      for (int r = 0; r < 4; r++) acc[dt][r] *= alpha;
      const short8 vf0 = *reinterpret_cast<const short8*>(Vs + (dt * 16 + l16) * 72 + quad * 8);
      const short8 vf1 = *reinterpret_cast<const short8*>(Vs + (dt * 16 + l16) * 72 + 32 + quad * 8);
      acc[dt] = __builtin_amdgcn_mfma_f32_16x16x32_bf16(vf0, pf0, acc[dt], 0, 0, 0);
      acc[dt] = __builtin_amdgcn_mfma_f32_16x16x32_bf16(vf1, pf1, acc[dt], 0, 0, 0);
    }
  }

  // epilogue: O^T regs hold d = dt*16+quad*4+r for query l16 -> 4 consecutive d = 8B stores
  const float inv = (lsum > 0.f) ? 1.f / lsum : 0.f;
  unsigned short* orow = ctx + ((size_t)(b * LSEQ + qy)) * D_MODEL + h * DH;
  #pragma unroll
  for (int dt = 0; dt < 4; dt++) {
    uint2 o;
    o.x = pack_bf16(acc[dt][0] * inv, acc[dt][1] * inv);
    o.y = pack_bf16(acc[dt][2] * inv, acc[dt][3] * inv);
    *reinterpret_cast<uint2*>(orow + dt * 16 + quad * 4) = o;
  }
}

// ---------------------------------------------------------------- launch
extern "C" void kernel_launch(void* const* d_in, const int* in_sizes, int n_in,
                              void* d_out, int out_size, void* d_ws, size_t ws_size,
                              hipStream_t stream) {
  const float* x      = (const float*)d_in[0];
  const int*   sid    = (const int*)d_in[1];
  const float* ln_w   = (const float*)d_in[2];
  const float* ln_b   = (const float*)d_in[3];
  const float* w_qkv  = (const float*)d_in[4];
  const float* q_ln_w = (const float*)d_in[5];
  const float* k_ln_w = (const float*)d_in[6];
  const float* w_out  = (const float*)d_in[7];
  float* out = (float*)d_out;
  char* ws = (char*)d_ws;

  constexpr size_t OFF_WQKVT = 0;                        //  6,291,456
  constexpr size_t OFF_WOUTT = 6291456;                  //  2,097,152
  constexpr size_t OFF_H     = 8388608;                  // 16,777,216
  constexpr size_t OFF_QKV   = 25165824;                 // 50,331,648 (bf16)
  constexpr size_t OFF_QT    = 75497472;                 // 16,777,216
  constexpr size_t OFF_KT    = 92274688;                 // 16,777,216
  constexpr size_t OFF_VN    = 109051904;                // 16,777,216
  constexpr size_t OFF_VT    = 125829120;                // 16,777,216
  constexpr size_t OFF_CTX   = 142606336;                // 16,777,216
  constexpr size_t OFF_SEGS  = 159383552;                // 32,768
  constexpr size_t OFF_SEGE  = 159416320;                // 32,768

  __hip_bfloat16* wqkvT = (__hip_bfloat16*)(ws + OFF_WQKVT);
  __hip_bfloat16* woutT = (__hip_bfloat16*)(ws + OFF_WOUTT);
  __hip_bfloat16* hbuf  = (__hip_bfloat16*)(ws + OFF_H);
  __hip_bfloat16* qkvb  = (__hip_bfloat16*)(ws + OFF_QKV);
  unsigned short* qTb   = (unsigned short*)(ws + OFF_QT);
  unsigned short* kTb   = (unsigned short*)(ws + OFF_KT);
  unsigned short* vNb   = (unsigned short*)(ws + OFF_VN);
  unsigned short* vTb   = (unsigned short*)(ws + OFF_VT);
  unsigned short* ctx   = (unsigned short*)(ws + OFF_CTX);
  int*            segst = (int*)(ws + OFF_SEGS);
  int*            segen = (int*)(ws + OFF_SEGE);

  transpose_cast<<<dim3(96, 32), dim3(32, 8), 0, stream>>>(w_qkv, wqkvT, 1024, 3072);
  transpose_cast<<<dim3(32, 32), dim3(32, 8), 0, stream>>>(w_out, woutT, 1024, 1024);
  ln_kernel<<<NTOK, 256, 0, stream>>>(x, ln_w, ln_b, hbuf);
  gemm_bt<__hip_bfloat16><<<dim3(K3 / 128, NTOK / 128), 256, 0, stream>>>(
      hbuf, wqkvT, qkvb, NTOK, K3, 1024);
  seg_kernel<<<NTOK / 256, 256, 0, stream>>>(sid, segst, segen);
  rope_kernel<<<NTOK, 256, 0, stream>>>((const unsigned short*)qkvb, q_ln_w, k_ln_w,
                                        qTb, kTb, vNb);
  vtrans<<<dim3(LSEQ / 64, BATCH * NH), 256, 0, stream>>>(vNb, vTb);
  attn_mfma<<<dim3(LSEQ / 64, NH, BATCH), 256, 0, stream>>>(qTb, kTb, vTb, segst, segen, ctx);
  gemm_bt<float><<<dim3(D_MODEL / 128, NTOK / 128), 256, 0, stream>>>(
      (const __hip_bfloat16*)ctx, woutT, out, NTOK, D_MODEL, 1024);
}

// Round 6
// 279.334 us; speedup vs baseline: 1.2174x; 1.0290x over previous
//
#include <hip/hip_runtime.h>
#include <hip/hip_bf16.h>
#include <cstdint>
#include <cstddef>
#include <type_traits>

#define D_MODEL 1024
#define NH      16
#define DH      64
#define LSEQ    2048
#define BATCH   4
#define NTOK    8192      // BATCH * LSEQ
#define K3      3072

typedef __attribute__((ext_vector_type(8))) short  short8;
typedef __attribute__((ext_vector_type(4))) float  floatx4;

__device__ __forceinline__ unsigned short f2bf_bits(float f) {
  __hip_bfloat16 h = __float2bfloat16(f);
  return __builtin_bit_cast(unsigned short, h);
}
__device__ __forceinline__ float bf2f(unsigned short u) {
  return __bfloat162float(__builtin_bit_cast(__hip_bfloat16, u));
}
__device__ __forceinline__ unsigned int pack_bf16(float lo, float hi) {
  return (unsigned int)f2bf_bits(lo) | ((unsigned int)f2bf_bits(hi) << 16);
}

__device__ __forceinline__ void gld_lds16(const void* g, void* l) {
  __builtin_amdgcn_global_load_lds(
      (const __attribute__((address_space(1))) void*)g,
      (__attribute__((address_space(3))) void*)l,
      16, 0, 0);
}

// ---------------------------------------------------------------- transpose+cast
// src: fp32 [R][C] -> dst: bf16 [C][R]
__global__ __launch_bounds__(256)
void transpose_cast(const float* __restrict__ src, __hip_bfloat16* __restrict__ dst,
                    int R, int C) {
  __shared__ float tile[32][33];
  const int c0 = blockIdx.x * 32, r0 = blockIdx.y * 32;
  const int x = threadIdx.x, y = threadIdx.y;   // 32 x 8
  #pragma unroll
  for (int j = 0; j < 32; j += 8)
    tile[y + j][x] = src[(size_t)(r0 + y + j) * C + c0 + x];
  __syncthreads();
  #pragma unroll
  for (int j = 0; j < 32; j += 8)
    dst[(size_t)(c0 + y + j) * R + r0 + x] = __float2bfloat16(tile[x][y + j]);
}

// ---------------------------------------------------------------- LayerNorm(x) -> bf16
__global__ __launch_bounds__(256)
void ln_kernel(const float* __restrict__ x, const float* __restrict__ w,
               const float* __restrict__ bb, __hip_bfloat16* __restrict__ h) {
  const int t = blockIdx.x, tid = threadIdx.x;
  const float4 v = reinterpret_cast<const float4*>(x + (size_t)t * D_MODEL)[tid];
  float s  = v.x + v.y + v.z + v.w;
  float ss = v.x*v.x + v.y*v.y + v.z*v.z + v.w*v.w;
  #pragma unroll
  for (int off = 32; off > 0; off >>= 1) {
    s  += __shfl_down(s, off);
    ss += __shfl_down(ss, off);
  }
  __shared__ float red[8];
  if ((tid & 63) == 0) { red[(tid >> 6) * 2] = s; red[(tid >> 6) * 2 + 1] = ss; }
  __syncthreads();
  s  = red[0] + red[2] + red[4] + red[6];
  ss = red[1] + red[3] + red[5] + red[7];
  const float mu  = s * (1.f / D_MODEL);
  const float var = ss * (1.f / D_MODEL) - mu * mu;
  const float rs  = rsqrtf(var + 1e-5f);
  const float4 wv = reinterpret_cast<const float4*>(w)[tid];
  const float4 bv = reinterpret_cast<const float4*>(bb)[tid];
  ushort4 o;
  o.x = f2bf_bits((v.x - mu) * rs * wv.x + bv.x);
  o.y = f2bf_bits((v.y - mu) * rs * wv.y + bv.y);
  o.z = f2bf_bits((v.z - mu) * rs * wv.z + bv.z);
  o.w = f2bf_bits((v.w - mu) * rs * wv.w + bv.w);
  reinterpret_cast<ushort4*>(h + (size_t)t * D_MODEL)[tid] = o;
}

// ---------------------------------------------------------------- bf16 GEMM, Bt layout
// A: bf16 [M][K] row-major, Bt: bf16 [N][K] (B transposed), C: OutT [M][N]
// BK=64, XOR-swizzled LDS (chunk c stored in slot q = c ^ (row&7)) to kill
// bank conflicts on the 128-B-stride fragment reads while keeping the
// global_load_lds lane-ordered destination contract.
template <typename OutT>
__global__ __launch_bounds__(256, 2)
void gemm_bt(const __hip_bfloat16* __restrict__ A, const __hip_bfloat16* __restrict__ Bt,
             OutT* __restrict__ C, int M, int N, int K) {
  const int tid  = threadIdx.x;
  const int lane = tid & 63;
  const int wave = tid >> 6;
  const int bm = blockIdx.y * 128;
  const int bn = blockIdx.x * 128;
  const int wm = (wave & 1) * 64;
  const int wn = (wave >> 1) * 64;
  const int quad = lane >> 4;
  const int l16  = lane & 15;

  __shared__ __align__(16) __hip_bfloat16 As[128 * 64];
  __shared__ __align__(16) __hip_bfloat16 Bs[128 * 64];

  floatx4 acc[4][4];
  #pragma unroll
  for (int i = 0; i < 4; i++)
    #pragma unroll
    for (int j = 0; j < 4; j++) {
      floatx4 z = {0.f, 0.f, 0.f, 0.f};
      acc[i][j] = z;
    }

  // staging: thread -> (row = tid>>3 + 32*pass, slot q = tid&7), fetches chunk q^(row&7)
  const int srow = tid >> 3;
  const int sq   = tid & 7;
  const int sc8  = (sq ^ (srow & 7)) * 8;    // element offset of fetched chunk
  const __hip_bfloat16* Ab = A  + (size_t)(bm + srow) * K + sc8;
  const __hip_bfloat16* Bb = Bt + (size_t)(bn + srow) * K + sc8;

  const int axr = l16 & 7;                   // fragment-read swizzle key

  for (int k0 = 0; k0 < K; k0 += 64) {
    __syncthreads();
    #pragma unroll
    for (int p = 0; p < 4; p++) {
      gld_lds16(Ab + (size_t)(p * 32) * K + k0, (char*)As + p * 4096 + tid * 16);
      gld_lds16(Bb + (size_t)(p * 32) * K + k0, (char*)Bs + p * 4096 + tid * 16);
    }
    __syncthreads();
    #pragma unroll
    for (int s0 = 0; s0 < 2; s0++) {
      const int qo = ((s0 * 4 + quad) ^ axr) * 8;   // swizzled slot offset (elements)
      short8 af[4], bfr[4];
      #pragma unroll
      for (int i = 0; i < 4; i++)
        af[i] = *reinterpret_cast<const short8*>(As + (wm + i * 16 + l16) * 64 + qo);
      #pragma unroll
      for (int j = 0; j < 4; j++)
        bfr[j] = *reinterpret_cast<const short8*>(Bs + (wn + j * 16 + l16) * 64 + qo);
      #pragma unroll
      for (int i = 0; i < 4; i++)
        #pragma unroll
        for (int j = 0; j < 4; j++)
          acc[i][j] = __builtin_amdgcn_mfma_f32_16x16x32_bf16(af[i], bfr[j], acc[i][j], 0, 0, 0);
    }
  }

  #pragma unroll
  for (int i = 0; i < 4; i++)
    #pragma unroll
    for (int j = 0; j < 4; j++) {
      const int row0 = bm + wm + i * 16 + quad * 4;
      const int col  = bn + wn + j * 16 + l16;
      #pragma unroll
      for (int r = 0; r < 4; r++) {
        if constexpr (std::is_same<OutT, __hip_bfloat16>::value)
          C[(size_t)(row0 + r) * N + col] = __float2bfloat16(acc[i][j][r]);
        else
          C[(size_t)(row0 + r) * N + col] = acc[i][j][r];
      }
    }
}

// ---------------------------------------------------------------- segment bounds
__global__ __launch_bounds__(256)
void seg_kernel(const int* __restrict__ sid, int* __restrict__ segstart,
                int* __restrict__ segend) {
  const int i = blockIdx.x * 256 + threadIdx.x;   // 0..8191
  const int b = i >> 11, l = i & 2047;
  const int* row = sid + (size_t)b * LSEQ;
  const int v = row[l];
  int lo = 0, hi = l;
  while (lo < hi) { int mid = (lo + hi) >> 1; if (row[mid] < v) lo = mid + 1; else hi = mid; }
  segstart[i] = lo;
  lo = l + 1; hi = LSEQ;
  while (lo < hi) { int mid = (lo + hi) >> 1; if (row[mid] <= v) lo = mid + 1; else hi = mid; }
  segend[i] = lo;
}

// ---------------------------------------------------------------- QK-LN + RoPE + scatter (bf16 in/out)
// qkv: bf16 [NTOK][3072]; outputs bf16 [B][H][L][DH]; Q pre-scaled by 1/8.
// V untouched here (pure reshape — handled by vtrans directly from qkv).
__global__ __launch_bounds__(256)
void rope_kernel(const unsigned short* __restrict__ qkv, const float* __restrict__ qw,
                 const float* __restrict__ kw, unsigned short* __restrict__ qT,
                 unsigned short* __restrict__ kT) {
  const int t = blockIdx.x, tid = threadIdx.x;
  const int b = t >> 11, l = t & 2047;
  const unsigned short* row = qkv + (size_t)t * K3;
  const ushort4 qu = reinterpret_cast<const ushort4*>(row)[tid];
  const ushort4 ku = reinterpret_cast<const ushort4*>(row + 1024)[tid];
  const float4 q4 = make_float4(bf2f(qu.x), bf2f(qu.y), bf2f(qu.z), bf2f(qu.w));
  const float4 k4 = make_float4(bf2f(ku.x), bf2f(ku.y), bf2f(ku.z), bf2f(ku.w));
  float qs  = q4.x + q4.y + q4.z + q4.w;
  float qss = q4.x*q4.x + q4.y*q4.y + q4.z*q4.z + q4.w*q4.w;
  float ks  = k4.x + k4.y + k4.z + k4.w;
  float kss = k4.x*k4.x + k4.y*k4.y + k4.z*k4.z + k4.w*k4.w;
  #pragma unroll
  for (int off = 32; off > 0; off >>= 1) {
    qs  += __shfl_down(qs, off);  qss += __shfl_down(qss, off);
    ks  += __shfl_down(ks, off);  kss += __shfl_down(kss, off);
  }
  __shared__ float red[16];
  const int w = tid >> 6;
  if ((tid & 63) == 0) {
    red[w*4] = qs; red[w*4+1] = qss; red[w*4+2] = ks; red[w*4+3] = kss;
  }
  __syncthreads();
  qs  = red[0] + red[4] + red[8]  + red[12];
  qss = red[1] + red[5] + red[9]  + red[13];
  ks  = red[2] + red[6] + red[10] + red[14];
  kss = red[3] + red[7] + red[11] + red[15];
  const float qmu = qs * (1.f/1024), qvar = qss * (1.f/1024) - qmu*qmu;
  const float qrs = rsqrtf(qvar + 1e-5f);
  const float kmu = ks * (1.f/1024), kvar = kss * (1.f/1024) - kmu*kmu;
  const float krs = rsqrtf(kvar + 1e-5f);

  __shared__ float qn[1024];
  __shared__ float kn[1024];
  const float4 qwv = reinterpret_cast<const float4*>(qw)[tid];
  const float4 kwv = reinterpret_cast<const float4*>(kw)[tid];
  const int d = tid * 4;
  qn[d+0] = (q4.x - qmu) * qrs * qwv.x;
  qn[d+1] = (q4.y - qmu) * qrs * qwv.y;
  qn[d+2] = (q4.z - qmu) * qrs * qwv.z;
  qn[d+3] = (q4.w - qmu) * qrs * qwv.w;
  kn[d+0] = (k4.x - kmu) * krs * kwv.x;
  kn[d+1] = (k4.y - kmu) * krs * kwv.y;
  kn[d+2] = (k4.z - kmu) * krs * kwv.z;
  kn[d+3] = (k4.w - kmu) * krs * kwv.w;
  __syncthreads();

  const int hh = d >> 6, dh = d & 63;
  float oq[4], ok[4];
  #pragma unroll
  for (int i = 0; i < 4; i++) {
    const int dd = dh + i;
    const int j = dd & 31;
    const float th = (float)l * __expf(-(float)j * 0.28782313662425575f); // ln(1e4)/32
    const float cs = cosf(th), sn = sinf(th);
    const float qp = (dd < 32) ? -qn[d + i + 32] : qn[d + i - 32];
    const float kp = (dd < 32) ? -kn[d + i + 32] : kn[d + i - 32];
    oq[i] = (qn[d + i] * cs + qp * sn) * 0.125f;   // fold 1/sqrt(Dh) into Q
    ok[i] = kn[d + i] * cs + kp * sn;
  }
  const size_t ob = ((size_t)(b * NH + hh) * LSEQ + l) * DH + dh;
  ushort4 pq, pk;
  pq.x = f2bf_bits(oq[0]); pq.y = f2bf_bits(oq[1]); pq.z = f2bf_bits(oq[2]); pq.w = f2bf_bits(oq[3]);
  pk.x = f2bf_bits(ok[0]); pk.y = f2bf_bits(ok[1]); pk.z = f2bf_bits(ok[2]); pk.w = f2bf_bits(ok[3]);
  *reinterpret_cast<ushort4*>(qT + ob) = pq;
  *reinterpret_cast<ushort4*>(kT + ob) = pk;
}

// ---------------------------------------------------------------- V transpose per (b,h), direct from qkv
// qkv: bf16 [NTOK][3072] (V at column 2048 + h*64 + dh) -> vT: bf16 [BH][DH][L]
__global__ __launch_bounds__(256)
void vtrans(const unsigned short* __restrict__ qkv, unsigned short* __restrict__ vT) {
  __shared__ __align__(16) unsigned short T[64 * 72];
  const int bh = blockIdx.y;
  const int b = bh >> 4, h = bh & 15;
  const int l0 = blockIdx.x * 64;
  const int tid = threadIdx.x;
  #pragma unroll
  for (int it = 0; it < 2; it++) {
    const int cid = tid + it * 256;
    const int r = cid >> 3, c = (cid & 7) * 8;
    *reinterpret_cast<short8*>(T + r * 72 + c) =
        *reinterpret_cast<const short8*>(qkv + (size_t)(b * LSEQ + l0 + r) * K3
                                         + 2048 + h * DH + c);
  }
  __syncthreads();
  #pragma unroll
  for (int it = 0; it < 2; it++) {
    const int cid = tid + it * 256;
    const int dh = cid >> 3, c = (cid & 7) * 8;
    short8 o;
    #pragma unroll
    for (int e = 0; e < 8; e++) o[e] = (short)T[(c + e) * 72 + dh];
    *reinterpret_cast<short8*>(vT + ((size_t)bh * DH + dh) * LSEQ + l0 + c) = o;
  }
}

// ---------------------------------------------------------------- MFMA flash attention
// S^T-form softmax + cooperative LDS staging of K/V tiles.
// qT,kT: bf16 [BH][L][DH] (Q pre-scaled); vT: bf16 [BH][DH][L]; ctx: bf16 [B][L][H*DH]
__global__ __launch_bounds__(256)
void attn_mfma(const unsigned short* __restrict__ qT, const unsigned short* __restrict__ kT,
               const unsigned short* __restrict__ vT, const int* __restrict__ segs,
               const int* __restrict__ sege, unsigned short* __restrict__ ctx) {
  const int tid  = threadIdx.x;
  const int lane = tid & 63, w = tid >> 6;
  const int quad = lane >> 4, l16 = lane & 15;
  const int qbase = blockIdx.x * 64;
  const int h = blockIdx.y, b = blockIdx.z;
  const int qy = qbase + w * 16 + l16;            // this lane's query (same across quads)
  const size_t bh = (size_t)(b * NH + h);
  const unsigned short* Kg = kT + bh * LSEQ * DH;
  const unsigned short* Vg = vT + bh * DH * LSEQ;

  __shared__ __align__(16) unsigned short Ks[64 * 72];   // K rows [key][dh]
  __shared__ __align__(16) unsigned short Vs[64 * 72];   // V^T rows [dh][key]
  __shared__ __align__(16) unsigned short Ps[4][16 * 72];

  // Q as B-operand: B[k=dh][n=q]; one-time direct load
  const unsigned short* Qrow = qT + (bh * LSEQ + qy) * DH;
  const short8 qf0 = *reinterpret_cast<const short8*>(Qrow + quad * 8);
  const short8 qf1 = *reinterpret_cast<const short8*>(Qrow + 32 + quad * 8);

  const int st = segs[b * LSEQ + qy];
  const int en = sege[b * LSEQ + qy];
  const unsigned span = (unsigned)(en - st);
  // block range (sequence_ids sorted => first query's start is min, last's end is max)
  const int kmin = segs[b * LSEQ + qbase] & ~63;
  const int kmax = sege[b * LSEQ + qbase + 63];
  // this wave's range (for skipping tiles)
  const int wmin = segs[b * LSEQ + qbase + w * 16];
  const int wmax = sege[b * LSEQ + qbase + w * 16 + 15];

  floatx4 acc[4];
  #pragma unroll
  for (int dt = 0; dt < 4; dt++) { floatx4 z = {0.f,0.f,0.f,0.f}; acc[dt] = z; }
  float m = -1e30f, lsum = 0.f;

  const int r_ = tid >> 3, c_ = (tid & 7) * 8;   // staging coords (row 0..31 per iter half)

  for (int kk = kmin; kk < kmax; kk += 64) {
    __syncthreads();
    #pragma unroll
    for (int it = 0; it < 2; it++) {
      const int r = r_ + it * 32;
      *reinterpret_cast<short8*>(Ks + r * 72 + c_) =
          *reinterpret_cast<const short8*>(Kg + (size_t)(kk + r) * DH + c_);
      *reinterpret_cast<short8*>(Vs + r * 72 + c_) =
          *reinterpret_cast<const short8*>(Vg + (size_t)r * LSEQ + kk + c_);
    }
    __syncthreads();

    if (kk + 64 <= wmin || kk >= wmax) continue;   // tile fully outside this wave's span

    // S^T = K Q^T : 4 key-subtiles of 16; C layout row=key(quad*4+reg), col=q(l16)
    floatx4 sc[4];
    #pragma unroll
    for (int t = 0; t < 4; t++) {
      const short8 kf0 = *reinterpret_cast<const short8*>(Ks + (t * 16 + l16) * 72 + quad * 8);
      const short8 kf1 = *reinterpret_cast<const short8*>(Ks + (t * 16 + l16) * 72 + 32 + quad * 8);
      floatx4 z = {0.f,0.f,0.f,0.f};
      sc[t] = __builtin_amdgcn_mfma_f32_16x16x32_bf16(kf0, qf0, z, 0, 0, 0);
      sc[t] = __builtin_amdgcn_mfma_f32_16x16x32_bf16(kf1, qf1, sc[t], 0, 0, 0);
    }

    // mask + in-lane max over 16 keys, then 2 shfls across quads
    float vm = -1e30f;
    #pragma unroll
    for (int t = 0; t < 4; t++) {
      const int k0 = kk + t * 16 + quad * 4;
      #pragma unroll
      for (int r = 0; r < 4; r++) {
        const bool ok = (unsigned)(k0 + r - st) < span;
        sc[t][r] = ok ? sc[t][r] : -1e30f;
        vm = fmaxf(vm, sc[t][r]);
      }
    }
    vm = fmaxf(vm, __shfl_xor(vm, 16));
    vm = fmaxf(vm, __shfl_xor(vm, 32));
    const float mn = fmaxf(m, vm);
    const float alpha = __expf(m - mn);
    m = mn;

    // exp + pack 4 consecutive keys -> one b64 LDS write per subtile
    float rs = 0.f;
    #pragma unroll
    for (int t = 0; t < 4; t++) {
      float p0 = (sc[t][0] > -1e29f) ? __expf(sc[t][0] - mn) : 0.f;
      float p1 = (sc[t][1] > -1e29f) ? __expf(sc[t][1] - mn) : 0.f;
      float p2 = (sc[t][2] > -1e29f) ? __expf(sc[t][2] - mn) : 0.f;
      float p3 = (sc[t][3] > -1e29f) ? __expf(sc[t][3] - mn) : 0.f;
      rs += (p0 + p1) + (p2 + p3);
      uint2 pk;
      pk.x = pack_bf16(p0, p1);
      pk.y = pack_bf16(p2, p3);
      *reinterpret_cast<uint2*>(&Ps[w][l16 * 72 + t * 16 + quad * 4]) = pk;
    }
    rs += __shfl_xor(rs, 16);
    rs += __shfl_xor(rs, 32);
    lsum = lsum * alpha + rs;

    // read P back as B-operand rows [q=l16][k-chunk] (intra-wave, no barrier)
    const short8 pf0 = *reinterpret_cast<const short8*>(&Ps[w][l16 * 72 + quad * 8]);
    const short8 pf1 = *reinterpret_cast<const short8*>(&Ps[w][l16 * 72 + 32 + quad * 8]);

    // O^T = alpha*O^T + V^T P^T : A = V^T rows (from LDS)
    #pragma unroll
    for (int dt = 0; dt < 4; dt++) {
      #pragma unroll
      for (int r = 0; r < 4; r++) acc[dt][r] *= alpha;
      const short8 vf0 = *reinterpret_cast<const short8*>(Vs + (dt * 16 + l16) * 72 + quad * 8);
      const short8 vf1 = *reinterpret_cast<const short8*>(Vs + (dt * 16 + l16) * 72 + 32 + quad * 8);
      acc[dt] = __builtin_amdgcn_mfma_f32_16x16x32_bf16(vf0, pf0, acc[dt], 0, 0, 0);
      acc[dt] = __builtin_amdgcn_mfma_f32_16x16x32_bf16(vf1, pf1, acc[dt], 0, 0, 0);
    }
  }

  // epilogue: O^T regs hold d = dt*16+quad*4+r for query l16 -> 4 consecutive d = 8B stores
  const float inv = (lsum > 0.f) ? 1.f / lsum : 0.f;
  unsigned short* orow = ctx + ((size_t)(b * LSEQ + qy)) * D_MODEL + h * DH;
  #pragma unroll
  for (int dt = 0; dt < 4; dt++) {
    uint2 o;
    o.x = pack_bf16(acc[dt][0] * inv, acc[dt][1] * inv);
    o.y = pack_bf16(acc[dt][2] * inv, acc[dt][3] * inv);
    *reinterpret_cast<uint2*>(orow + dt * 16 + quad * 4) = o;
  }
}

// ---------------------------------------------------------------- launch
extern "C" void kernel_launch(void* const* d_in, const int* in_sizes, int n_in,
                              void* d_out, int out_size, void* d_ws, size_t ws_size,
                              hipStream_t stream) {
  const float* x      = (const float*)d_in[0];
  const int*   sid    = (const int*)d_in[1];
  const float* ln_w   = (const float*)d_in[2];
  const float* ln_b   = (const float*)d_in[3];
  const float* w_qkv  = (const float*)d_in[4];
  const float* q_ln_w = (const float*)d_in[5];
  const float* k_ln_w = (const float*)d_in[6];
  const float* w_out  = (const float*)d_in[7];
  float* out = (float*)d_out;
  char* ws = (char*)d_ws;

  constexpr size_t OFF_WQKVT = 0;                        //  6,291,456
  constexpr size_t OFF_WOUTT = 6291456;                  //  2,097,152
  constexpr size_t OFF_H     = 8388608;                  // 16,777,216
  constexpr size_t OFF_QKV   = 25165824;                 // 50,331,648 (bf16)
  constexpr size_t OFF_QT    = 75497472;                 // 16,777,216
  constexpr size_t OFF_KT    = 92274688;                 // 16,777,216
  constexpr size_t OFF_VT    = 109051904;                // 16,777,216
  constexpr size_t OFF_CTX   = 125829120;                // 16,777,216
  constexpr size_t OFF_SEGS  = 142606336;                // 32,768
  constexpr size_t OFF_SEGE  = 142639104;                // 32,768

  __hip_bfloat16* wqkvT = (__hip_bfloat16*)(ws + OFF_WQKVT);
  __hip_bfloat16* woutT = (__hip_bfloat16*)(ws + OFF_WOUTT);
  __hip_bfloat16* hbuf  = (__hip_bfloat16*)(ws + OFF_H);
  __hip_bfloat16* qkvb  = (__hip_bfloat16*)(ws + OFF_QKV);
  unsigned short* qTb   = (unsigned short*)(ws + OFF_QT);
  unsigned short* kTb   = (unsigned short*)(ws + OFF_KT);
  unsigned short* vTb   = (unsigned short*)(ws + OFF_VT);
  unsigned short* ctx   = (unsigned short*)(ws + OFF_CTX);
  int*            segst = (int*)(ws + OFF_SEGS);
  int*            segen = (int*)(ws + OFF_SEGE);

  transpose_cast<<<dim3(96, 32), dim3(32, 8), 0, stream>>>(w_qkv, wqkvT, 1024, 3072);
  transpose_cast<<<dim3(32, 32), dim3(32, 8), 0, stream>>>(w_out, woutT, 1024, 1024);
  ln_kernel<<<NTOK, 256, 0, stream>>>(x, ln_w, ln_b, hbuf);
  gemm_bt<__hip_bfloat16><<<dim3(K3 / 128, NTOK / 128), 256, 0, stream>>>(
      hbuf, wqkvT, qkvb, NTOK, K3, 1024);
  seg_kernel<<<NTOK / 256, 256, 0, stream>>>(sid, segst, segen);
  rope_kernel<<<NTOK, 256, 0, stream>>>((const unsigned short*)qkvb, q_ln_w, k_ln_w,
                                        qTb, kTb);
  vtrans<<<dim3(LSEQ / 64, BATCH * NH), 256, 0, stream>>>((const unsigned short*)qkvb, vTb);
  attn_mfma<<<dim3(LSEQ / 64, NH, BATCH), 256, 0, stream>>>(qTb, kTb, vTb, segst, segen, ctx);
  gemm_bt<float><<<dim3(D_MODEL / 128, NTOK / 128), 256, 0, stream>>>(
      (const __hip_bfloat16*)ctx, woutT, out, NTOK, D_MODEL, 1024);
}

// Round 7
// 261.993 us; speedup vs baseline: 1.2980x; 1.0662x over previous
//
#include <hip/hip_runtime.h>
#include <hip/hip_bf16.h>
#include <cstdint>
#include <cstddef>
#include <type_traits>

#define D_MODEL 1024
#define NH      16
#define DH      64
#define LSEQ    2048
#define BATCH   4
#define NTOK    8192      // BATCH * LSEQ
#define K3      3072

typedef __attribute__((ext_vector_type(8))) short  short8;
typedef __attribute__((ext_vector_type(4))) float  floatx4;

__device__ __forceinline__ unsigned short f2bf_bits(float f) {
  __hip_bfloat16 h = __float2bfloat16(f);
  return __builtin_bit_cast(unsigned short, h);
}
__device__ __forceinline__ float bf2f(unsigned short u) {
  return __bfloat162float(__builtin_bit_cast(__hip_bfloat16, u));
}
__device__ __forceinline__ unsigned int pack_bf16(float lo, float hi) {
  return (unsigned int)f2bf_bits(lo) | ((unsigned int)f2bf_bits(hi) << 16);
}

__device__ __forceinline__ void gld_lds16(const void* g, void* l) {
  __builtin_amdgcn_global_load_lds(
      (const __attribute__((address_space(1))) void*)g,
      (__attribute__((address_space(3))) void*)l,
      16, 0, 0);
}

// ---------------------------------------------------------------- transpose+cast
// src: fp32 [R][C] -> dst: bf16 [C][R]
__global__ __launch_bounds__(256)
void transpose_cast(const float* __restrict__ src, __hip_bfloat16* __restrict__ dst,
                    int R, int C) {
  __shared__ float tile[32][33];
  const int c0 = blockIdx.x * 32, r0 = blockIdx.y * 32;
  const int x = threadIdx.x, y = threadIdx.y;   // 32 x 8
  #pragma unroll
  for (int j = 0; j < 32; j += 8)
    tile[y + j][x] = src[(size_t)(r0 + y + j) * C + c0 + x];
  __syncthreads();
  #pragma unroll
  for (int j = 0; j < 32; j += 8)
    dst[(size_t)(c0 + y + j) * R + r0 + x] = __float2bfloat16(tile[x][y + j]);
}

// ---------------------------------------------------------------- LayerNorm(x) -> bf16
// one wave per token: no LDS, no barrier
__global__ __launch_bounds__(256)
void ln_kernel(const float* __restrict__ x, const float* __restrict__ w,
               const float* __restrict__ bb, __hip_bfloat16* __restrict__ h) {
  const int lane = threadIdx.x & 63;
  const int t = blockIdx.x * 4 + (threadIdx.x >> 6);
  const float4* xr = reinterpret_cast<const float4*>(x) + (size_t)t * 256;
  float4 v[4];
  float s = 0.f, ss = 0.f;
  #pragma unroll
  for (int i = 0; i < 4; i++) {
    v[i] = xr[lane + i * 64];
    s  += (v[i].x + v[i].y) + (v[i].z + v[i].w);
    ss += (v[i].x*v[i].x + v[i].y*v[i].y) + (v[i].z*v[i].z + v[i].w*v[i].w);
  }
  #pragma unroll
  for (int off = 1; off < 64; off <<= 1) {
    s  += __shfl_xor(s, off);
    ss += __shfl_xor(ss, off);
  }
  const float mu = s * (1.f / 1024);
  const float rs = rsqrtf(ss * (1.f / 1024) - mu * mu + 1e-5f);
  const float4* wr = reinterpret_cast<const float4*>(w);
  const float4* br = reinterpret_cast<const float4*>(bb);
  ushort4* hr = reinterpret_cast<ushort4*>(h) + (size_t)t * 256;
  #pragma unroll
  for (int i = 0; i < 4; i++) {
    const float4 wv = wr[lane + i * 64];
    const float4 bv = br[lane + i * 64];
    ushort4 o;
    o.x = f2bf_bits((v[i].x - mu) * rs * wv.x + bv.x);
    o.y = f2bf_bits((v[i].y - mu) * rs * wv.y + bv.y);
    o.z = f2bf_bits((v[i].z - mu) * rs * wv.z + bv.z);
    o.w = f2bf_bits((v[i].w - mu) * rs * wv.w + bv.w);
    hr[lane + i * 64] = o;
  }
}

// ---------------------------------------------------------------- bf16 GEMM, Bt layout
// A: bf16 [M][K] row-major, Bt: bf16 [N][K] (B transposed), C: OutT [M][N]
// BK=64, XOR-swizzled LDS — unchanged from round 6 (conflict-free, 954 TF).
template <typename OutT>
__global__ __launch_bounds__(256, 2)
void gemm_bt(const __hip_bfloat16* __restrict__ A, const __hip_bfloat16* __restrict__ Bt,
             OutT* __restrict__ C, int M, int N, int K) {
  const int tid  = threadIdx.x;
  const int lane = tid & 63;
  const int wave = tid >> 6;
  const int bm = blockIdx.y * 128;
  const int bn = blockIdx.x * 128;
  const int wm = (wave & 1) * 64;
  const int wn = (wave >> 1) * 64;
  const int quad = lane >> 4;
  const int l16  = lane & 15;

  __shared__ __align__(16) __hip_bfloat16 As[128 * 64];
  __shared__ __align__(16) __hip_bfloat16 Bs[128 * 64];

  floatx4 acc[4][4];
  #pragma unroll
  for (int i = 0; i < 4; i++)
    #pragma unroll
    for (int j = 0; j < 4; j++) {
      floatx4 z = {0.f, 0.f, 0.f, 0.f};
      acc[i][j] = z;
    }

  const int srow = tid >> 3;
  const int sq   = tid & 7;
  const int sc8  = (sq ^ (srow & 7)) * 8;
  const __hip_bfloat16* Ab = A  + (size_t)(bm + srow) * K + sc8;
  const __hip_bfloat16* Bb = Bt + (size_t)(bn + srow) * K + sc8;

  const int axr = l16 & 7;

  for (int k0 = 0; k0 < K; k0 += 64) {
    __syncthreads();
    #pragma unroll
    for (int p = 0; p < 4; p++) {
      gld_lds16(Ab + (size_t)(p * 32) * K + k0, (char*)As + p * 4096 + tid * 16);
      gld_lds16(Bb + (size_t)(p * 32) * K + k0, (char*)Bs + p * 4096 + tid * 16);
    }
    __syncthreads();
    #pragma unroll
    for (int s0 = 0; s0 < 2; s0++) {
      const int qo = ((s0 * 4 + quad) ^ axr) * 8;
      short8 af[4], bfr[4];
      #pragma unroll
      for (int i = 0; i < 4; i++)
        af[i] = *reinterpret_cast<const short8*>(As + (wm + i * 16 + l16) * 64 + qo);
      #pragma unroll
      for (int j = 0; j < 4; j++)
        bfr[j] = *reinterpret_cast<const short8*>(Bs + (wn + j * 16 + l16) * 64 + qo);
      #pragma unroll
      for (int i = 0; i < 4; i++)
        #pragma unroll
        for (int j = 0; j < 4; j++)
          acc[i][j] = __builtin_amdgcn_mfma_f32_16x16x32_bf16(af[i], bfr[j], acc[i][j], 0, 0, 0);
    }
  }

  #pragma unroll
  for (int i = 0; i < 4; i++)
    #pragma unroll
    for (int j = 0; j < 4; j++) {
      const int row0 = bm + wm + i * 16 + quad * 4;
      const int col  = bn + wn + j * 16 + l16;
      #pragma unroll
      for (int r = 0; r < 4; r++) {
        if constexpr (std::is_same<OutT, __hip_bfloat16>::value)
          C[(size_t)(row0 + r) * N + col] = __float2bfloat16(acc[i][j][r]);
        else
          C[(size_t)(row0 + r) * N + col] = acc[i][j][r];
      }
    }
}

// ---------------------------------------------------------------- segment bounds (LDS-cached row)
__global__ __launch_bounds__(256)
void seg_kernel(const int* __restrict__ sid, int* __restrict__ segstart,
                int* __restrict__ segend) {
  __shared__ int srow[LSEQ];
  const int blk = blockIdx.x;          // 32 blocks: 8 per batch
  const int b = blk >> 3;
  const int tid = threadIdx.x;
  const int* row = sid + (size_t)b * LSEQ;
  #pragma unroll
  for (int i = 0; i < 8; i++) srow[tid + i * 256] = row[tid + i * 256];
  __syncthreads();
  const int l = (blk & 7) * 256 + tid;
  const int v = srow[l];
  int lo = 0, hi = l;
  while (lo < hi) { int mid = (lo + hi) >> 1; if (srow[mid] < v) lo = mid + 1; else hi = mid; }
  const int i = b * LSEQ + l;
  segstart[i] = lo;
  lo = l + 1; hi = LSEQ;
  while (lo < hi) { int mid = (lo + hi) >> 1; if (srow[mid] <= v) lo = mid + 1; else hi = mid; }
  segend[i] = lo;
}

// ---------------------------------------------------------------- QK-LN + RoPE (wave per token)
// Lane owns head hh=lane>>2, dims (jb..jb+7) and (jb+32..jb+39): RoPE pair is IN-LANE.
// One sincosf per lane builds the 32-entry angle table; fetched via __shfl.
// Q pre-scaled by 1/8. V untouched (vtrans reads qkv directly).
__global__ __launch_bounds__(256)
void rope_kernel(const unsigned short* __restrict__ qkv, const float* __restrict__ qw,
                 const float* __restrict__ kw, unsigned short* __restrict__ qT,
                 unsigned short* __restrict__ kT) {
  const int lane = threadIdx.x & 63;
  const int t = blockIdx.x * 4 + (threadIdx.x >> 6);
  const int b = t >> 11, l = t & 2047;
  const unsigned short* row = qkv + (size_t)t * K3;
  const int hh = lane >> 2;
  const int jb = (lane & 3) * 8;
  const int base = hh * 64 + jb;

  const short8 qa_u = *reinterpret_cast<const short8*>(row + base);
  const short8 qb_u = *reinterpret_cast<const short8*>(row + base + 32);
  const short8 ka_u = *reinterpret_cast<const short8*>(row + 1024 + base);
  const short8 kb_u = *reinterpret_cast<const short8*>(row + 1024 + base + 32);

  float qa[8], qb[8], ka[8], kb[8];
  float s_q = 0.f, ss_q = 0.f, s_k = 0.f, ss_k = 0.f;
  #pragma unroll
  for (int e = 0; e < 8; e++) {
    qa[e] = bf2f((unsigned short)qa_u[e]); qb[e] = bf2f((unsigned short)qb_u[e]);
    ka[e] = bf2f((unsigned short)ka_u[e]); kb[e] = bf2f((unsigned short)kb_u[e]);
    s_q  += qa[e] + qb[e];  ss_q += qa[e]*qa[e] + qb[e]*qb[e];
    s_k  += ka[e] + kb[e];  ss_k += ka[e]*ka[e] + kb[e]*kb[e];
  }
  #pragma unroll
  for (int off = 1; off < 64; off <<= 1) {
    s_q  += __shfl_xor(s_q, off);  ss_q += __shfl_xor(ss_q, off);
    s_k  += __shfl_xor(s_k, off);  ss_k += __shfl_xor(ss_k, off);
  }
  const float qmu = s_q * (1.f/1024);
  const float qrs = rsqrtf(ss_q * (1.f/1024) - qmu*qmu + 1e-5f);
  const float kmu = s_k * (1.f/1024);
  const float krs = rsqrtf(ss_k * (1.f/1024) - kmu*kmu + 1e-5f);

  // angle table: lane j0 in 0..31 computes (sin,cos) for frequency j0
  const int j0 = lane & 31;
  const float invf = __expf(-(float)j0 * 0.28782313662425575f);   // ln(1e4)/32
  float tsin, tcos;
  sincosf((float)l * invf, &tsin, &tcos);

  const float4 wq0 = *reinterpret_cast<const float4*>(qw + base);
  const float4 wq1 = *reinterpret_cast<const float4*>(qw + base + 4);
  const float4 wq2 = *reinterpret_cast<const float4*>(qw + base + 32);
  const float4 wq3 = *reinterpret_cast<const float4*>(qw + base + 36);
  const float4 wk0 = *reinterpret_cast<const float4*>(kw + base);
  const float4 wk1 = *reinterpret_cast<const float4*>(kw + base + 4);
  const float4 wk2 = *reinterpret_cast<const float4*>(kw + base + 32);
  const float4 wk3 = *reinterpret_cast<const float4*>(kw + base + 36);
  const float wqa[8] = {wq0.x,wq0.y,wq0.z,wq0.w, wq1.x,wq1.y,wq1.z,wq1.w};
  const float wqb[8] = {wq2.x,wq2.y,wq2.z,wq2.w, wq3.x,wq3.y,wq3.z,wq3.w};
  const float wka[8] = {wk0.x,wk0.y,wk0.z,wk0.w, wk1.x,wk1.y,wk1.z,wk1.w};
  const float wkb[8] = {wk2.x,wk2.y,wk2.z,wk2.w, wk3.x,wk3.y,wk3.z,wk3.w};

  short8 oqa, oqb, oka, okb;
  #pragma unroll
  for (int e = 0; e < 8; e++) {
    const int j = jb + e;
    const float c  = __shfl(tcos, j);
    const float sn = __shfl(tsin, j);
    const float qn1 = (qa[e] - qmu) * qrs * wqa[e];
    const float qn2 = (qb[e] - qmu) * qrs * wqb[e];
    const float kn1 = (ka[e] - kmu) * krs * wka[e];
    const float kn2 = (kb[e] - kmu) * krs * wkb[e];
    oqa[e] = (short)f2bf_bits((qn1 * c - qn2 * sn) * 0.125f);
    oqb[e] = (short)f2bf_bits((qn2 * c + qn1 * sn) * 0.125f);
    oka[e] = (short)f2bf_bits(kn1 * c - kn2 * sn);
    okb[e] = (short)f2bf_bits(kn2 * c + kn1 * sn);
  }
  const size_t ob = ((size_t)(b * NH + hh) * LSEQ + l) * DH + jb;
  *reinterpret_cast<short8*>(qT + ob)      = oqa;
  *reinterpret_cast<short8*>(qT + ob + 32) = oqb;
  *reinterpret_cast<short8*>(kT + ob)      = oka;
  *reinterpret_cast<short8*>(kT + ob + 32) = okb;
}

// ---------------------------------------------------------------- V transpose per (b,h)
// qkv V-part -> vT bf16 [BH][DH][L].  DMA staging + (row>>3)-XOR chunk swizzle.
__global__ __launch_bounds__(256)
void vtrans(const unsigned short* __restrict__ qkv, unsigned short* __restrict__ vT) {
  __shared__ __align__(16) unsigned short T[64 * 64];
  const int bh = blockIdx.y;
  const int b = bh >> 4, h = bh & 15;
  const int l0 = blockIdx.x * 64;
  const int tid = threadIdx.x;
  const int sr = tid >> 3, scc = tid & 7;
  const int r1 = sr + 32;
  gld_lds16(qkv + (size_t)(b * LSEQ + l0 + sr) * K3 + 2048 + h * 64 + ((scc ^ ((sr >> 3) & 7)) * 8),
            (char*)T + tid * 16);
  gld_lds16(qkv + (size_t)(b * LSEQ + l0 + r1) * K3 + 2048 + h * 64 + ((scc ^ ((r1 >> 3) & 7)) * 8),
            (char*)T + 4096 + tid * 16);
  __syncthreads();
  #pragma unroll
  for (int it = 0; it < 2; it++) {
    const int cid = tid + it * 256;
    const int dh = cid >> 3, c = (cid & 7) * 8;
    const int sl = (dh >> 3) ^ ((c >> 3) & 7);
    short8 o;
    #pragma unroll
    for (int e = 0; e < 8; e++)
      o[e] = (short)T[(c + e) * 64 + sl * 8 + (dh & 7)];
    *reinterpret_cast<short8*>(vT + ((size_t)bh * DH + dh) * LSEQ + l0 + c) = o;
  }
}

// ---------------------------------------------------------------- MFMA flash attention
// S^T-form softmax + DMA-staged, XOR-swizzled K/V tiles.
// qT,kT: bf16 [BH][L][DH] (Q pre-scaled); vT: bf16 [BH][DH][L]; ctx: bf16 [B][L][H*DH]
__global__ __launch_bounds__(256)
void attn_mfma(const unsigned short* __restrict__ qT, const unsigned short* __restrict__ kT,
               const unsigned short* __restrict__ vT, const int* __restrict__ segs,
               const int* __restrict__ sege, unsigned short* __restrict__ ctx) {
  const int tid  = threadIdx.x;
  const int lane = tid & 63, w = tid >> 6;
  const int quad = lane >> 4, l16 = lane & 15;
  const int qbase = blockIdx.x * 64;
  const int h = blockIdx.y, b = blockIdx.z;
  const int qy = qbase + w * 16 + l16;
  const size_t bh = (size_t)(b * NH + h);
  const unsigned short* Kg = kT + bh * LSEQ * DH;
  const unsigned short* Vg = vT + bh * DH * LSEQ;

  __shared__ __align__(16) unsigned short Ks[64 * 64];
  __shared__ __align__(16) unsigned short Vs[64 * 64];
  __shared__ __align__(16) unsigned short Ps[4][16 * 72];

  const unsigned short* Qrow = qT + (bh * LSEQ + qy) * DH;
  const short8 qf0 = *reinterpret_cast<const short8*>(Qrow + quad * 8);
  const short8 qf1 = *reinterpret_cast<const short8*>(Qrow + 32 + quad * 8);

  const int st = segs[b * LSEQ + qy];
  const int en = sege[b * LSEQ + qy];
  const unsigned span = (unsigned)(en - st);
  const int kmin = segs[b * LSEQ + qbase] & ~63;
  const int kmax = sege[b * LSEQ + qbase + 63];
  const int wmin = segs[b * LSEQ + qbase + w * 16];
  const int wmax = sege[b * LSEQ + qbase + w * 16 + 15];

  floatx4 acc[4];
  #pragma unroll
  for (int dt = 0; dt < 4; dt++) { floatx4 z = {0.f,0.f,0.f,0.f}; acc[dt] = z; }
  float m = -1e30f, lsum = 0.f;

  // staging: thread -> (row sr / sr+32, chunk-slot scc); source chunk XOR-permuted by row>>3
  const int sr  = tid >> 3, scc = tid & 7;
  const int r1  = sr + 32;
  const int sx0 = (scc ^ ((sr >> 3) & 7)) * 8;
  const int sx1 = (scc ^ ((r1 >> 3) & 7)) * 8;
  const int fx  = l16 >> 3;   // fragment-row swizzle component

  for (int kk = kmin; kk < kmax; kk += 64) {
    __syncthreads();
    gld_lds16(Kg + (size_t)(kk + sr) * DH + sx0, (char*)Ks + tid * 16);
    gld_lds16(Kg + (size_t)(kk + r1) * DH + sx1, (char*)Ks + 4096 + tid * 16);
    gld_lds16(Vg + (size_t)sr * LSEQ + kk + sx0, (char*)Vs + tid * 16);
    gld_lds16(Vg + (size_t)r1 * LSEQ + kk + sx1, (char*)Vs + 4096 + tid * 16);
    __syncthreads();

    if (kk + 64 <= wmin || kk >= wmax) continue;   // tile outside this wave's span

    // S^T = K Q^T : C layout row=key(quad*4+reg), col=q(l16)
    floatx4 sc[4];
    #pragma unroll
    for (int t = 0; t < 4; t++) {
      const int row = t * 16 + l16;
      const int kx = (2 * t + fx) & 7;
      const short8 kf0 = *reinterpret_cast<const short8*>(Ks + row * 64 + ((quad ^ kx) * 8));
      const short8 kf1 = *reinterpret_cast<const short8*>(Ks + row * 64 + (((quad + 4) ^ kx) * 8));
      floatx4 z = {0.f,0.f,0.f,0.f};
      sc[t] = __builtin_amdgcn_mfma_f32_16x16x32_bf16(kf0, qf0, z, 0, 0, 0);
      sc[t] = __builtin_amdgcn_mfma_f32_16x16x32_bf16(kf1, qf1, sc[t], 0, 0, 0);
    }

    // mask + in-lane max over 16 keys, then 2 shfls across quads
    float vm = -1e30f;
    #pragma unroll
    for (int t = 0; t < 4; t++) {
      const int k0 = kk + t * 16 + quad * 4;
      #pragma unroll
      for (int r = 0; r < 4; r++) {
        const bool ok = (unsigned)(k0 + r - st) < span;
        sc[t][r] = ok ? sc[t][r] : -1e30f;
        vm = fmaxf(vm, sc[t][r]);
      }
    }
    vm = fmaxf(vm, __shfl_xor(vm, 16));
    vm = fmaxf(vm, __shfl_xor(vm, 32));
    const float mn = fmaxf(m, vm);
    const float alpha = __expf(m - mn);
    m = mn;

    float rs = 0.f;
    #pragma unroll
    for (int t = 0; t < 4; t++) {
      float p0 = (sc[t][0] > -1e29f) ? __expf(sc[t][0] - mn) : 0.f;
      float p1 = (sc[t][1] > -1e29f) ? __expf(sc[t][1] - mn) : 0.f;
      float p2 = (sc[t][2] > -1e29f) ? __expf(sc[t][2] - mn) : 0.f;
      float p3 = (sc[t][3] > -1e29f) ? __expf(sc[t][3] - mn) : 0.f;
      rs += (p0 + p1) + (p2 + p3);
      uint2 pk;
      pk.x = pack_bf16(p0, p1);
      pk.y = pack_bf16(p2, p3);
      *reinterpret_cast<uint2*>(&Ps[w][l16 * 72 + t * 16 + quad * 4]) = pk;
    }
    rs += __shfl_xor(rs, 16);
    rs += __shfl_xor(rs, 32);
    lsum = lsum * alpha + rs;

    const short8 pf0 = *reinterpret_cast<const short8*>(&Ps[w][l16 * 72 + quad * 8]);
    const short8 pf1 = *reinterpret_cast<const short8*>(&Ps[w][l16 * 72 + 32 + quad * 8]);

    // O^T = alpha*O^T + V^T P^T
    #pragma unroll
    for (int dt = 0; dt < 4; dt++) {
      #pragma unroll
      for (int r = 0; r < 4; r++) acc[dt][r] *= alpha;
      const int row = dt * 16 + l16;
      const int vx = (2 * dt + fx) & 7;
      const short8 vf0 = *reinterpret_cast<const short8*>(Vs + row * 64 + ((quad ^ vx) * 8));
      const short8 vf1 = *reinterpret_cast<const short8*>(Vs + row * 64 + (((quad + 4) ^ vx) * 8));
      acc[dt] = __builtin_amdgcn_mfma_f32_16x16x32_bf16(vf0, pf0, acc[dt], 0, 0, 0);
      acc[dt] = __builtin_amdgcn_mfma_f32_16x16x32_bf16(vf1, pf1, acc[dt], 0, 0, 0);
    }
  }

  const float inv = (lsum > 0.f) ? 1.f / lsum : 0.f;
  unsigned short* orow = ctx + ((size_t)(b * LSEQ + qy)) * D_MODEL + h * DH;
  #pragma unroll
  for (int dt = 0; dt < 4; dt++) {
    uint2 o;
    o.x = pack_bf16(acc[dt][0] * inv, acc[dt][1] * inv);
    o.y = pack_bf16(acc[dt][2] * inv, acc[dt][3] * inv);
    *reinterpret_cast<uint2*>(orow + dt * 16 + quad * 4) = o;
  }
}

// ---------------------------------------------------------------- launch
extern "C" void kernel_launch(void* const* d_in, const int* in_sizes, int n_in,
                              void* d_out, int out_size, void* d_ws, size_t ws_size,
                              hipStream_t stream) {
  const float* x      = (const float*)d_in[0];
  const int*   sid    = (const int*)d_in[1];
  const float* ln_w   = (const float*)d_in[2];
  const float* ln_b   = (const float*)d_in[3];
  const float* w_qkv  = (const float*)d_in[4];
  const float* q_ln_w = (const float*)d_in[5];
  const float* k_ln_w = (const float*)d_in[6];
  const float* w_out  = (const float*)d_in[7];
  float* out = (float*)d_out;
  char* ws = (char*)d_ws;

  constexpr size_t OFF_WQKVT = 0;                        //  6,291,456
  constexpr size_t OFF_WOUTT = 6291456;                  //  2,097,152
  constexpr size_t OFF_H     = 8388608;                  // 16,777,216
  constexpr size_t OFF_QKV   = 25165824;                 // 50,331,648 (bf16)
  constexpr size_t OFF_QT    = 75497472;                 // 16,777,216
  constexpr size_t OFF_KT    = 92274688;                 // 16,777,216
  constexpr size_t OFF_VT    = 109051904;                // 16,777,216
  constexpr size_t OFF_CTX   = 125829120;                // 16,777,216
  constexpr size_t OFF_SEGS  = 142606336;                // 32,768
  constexpr size_t OFF_SEGE  = 142639104;                // 32,768

  __hip_bfloat16* wqkvT = (__hip_bfloat16*)(ws + OFF_WQKVT);
  __hip_bfloat16* woutT = (__hip_bfloat16*)(ws + OFF_WOUTT);
  __hip_bfloat16* hbuf  = (__hip_bfloat16*)(ws + OFF_H);
  __hip_bfloat16* qkvb  = (__hip_bfloat16*)(ws + OFF_QKV);
  unsigned short* qTb   = (unsigned short*)(ws + OFF_QT);
  unsigned short* kTb   = (unsigned short*)(ws + OFF_KT);
  unsigned short* vTb   = (unsigned short*)(ws + OFF_VT);
  unsigned short* ctx   = (unsigned short*)(ws + OFF_CTX);
  int*            segst = (int*)(ws + OFF_SEGS);
  int*            segen = (int*)(ws + OFF_SEGE);

  transpose_cast<<<dim3(96, 32), dim3(32, 8), 0, stream>>>(w_qkv, wqkvT, 1024, 3072);
  transpose_cast<<<dim3(32, 32), dim3(32, 8), 0, stream>>>(w_out, woutT, 1024, 1024);
  ln_kernel<<<NTOK / 4, 256, 0, stream>>>(x, ln_w, ln_b, hbuf);
  gemm_bt<__hip_bfloat16><<<dim3(K3 / 128, NTOK / 128), 256, 0, stream>>>(
      hbuf, wqkvT, qkvb, NTOK, K3, 1024);
  seg_kernel<<<32, 256, 0, stream>>>(sid, segst, segen);
  rope_kernel<<<NTOK / 4, 256, 0, stream>>>((const unsigned short*)qkvb, q_ln_w, k_ln_w,
                                            qTb, kTb);
  vtrans<<<dim3(LSEQ / 64, BATCH * NH), 256, 0, stream>>>((const unsigned short*)qkvb, vTb);
  attn_mfma<<<dim3(LSEQ / 64, NH, BATCH), 256, 0, stream>>>(qTb, kTb, vTb, segst, segen, ctx);
  gemm_bt<float><<<dim3(D_MODEL / 128, NTOK / 128), 256, 0, stream>>>(
      (const __hip_bfloat16*)ctx, woutT, out, NTOK, D_MODEL, 1024);
}

// Round 8
// 248.656 us; speedup vs baseline: 1.3676x; 1.0536x over previous
//
#include <hip/hip_runtime.h>
#include <hip/hip_bf16.h>
#include <cstdint>
#include <cstddef>
#include <type_traits>

#define D_MODEL 1024
#define NH      16
#define DH      64
#define LSEQ    2048
#define BATCH   4
#define NTOK    8192      // BATCH * LSEQ
#define K3      3072

typedef __attribute__((ext_vector_type(8))) short  short8;
typedef __attribute__((ext_vector_type(4))) float  floatx4;

__device__ __forceinline__ unsigned short f2bf_bits(float f) {
  __hip_bfloat16 h = __float2bfloat16(f);
  return __builtin_bit_cast(unsigned short, h);
}
__device__ __forceinline__ float bf2f(unsigned short u) {
  return __bfloat162float(__builtin_bit_cast(__hip_bfloat16, u));
}
__device__ __forceinline__ unsigned int pack_bf16(float lo, float hi) {
  return (unsigned int)f2bf_bits(lo) | ((unsigned int)f2bf_bits(hi) << 16);
}

__device__ __forceinline__ void gld_lds16(const void* g, void* l) {
  __builtin_amdgcn_global_load_lds(
      (const __attribute__((address_space(1))) void*)g,
      (__attribute__((address_space(3))) void*)l,
      16, 0, 0);
}

// ---------------------------------------------------------------- fused prologue
// blocks [0,3072): transpose+cast w_qkv [1024][3072] -> wqkvT [3072][1024]
// blocks [3072,4096): transpose+cast w_out [1024][1024] -> woutT
// blocks [4096,6144): LayerNorm(x) -> hbuf (4 tokens/block, wave per token)
// blocks [6144,6176): segment bounds
__global__ __launch_bounds__(256)
void prep_kernel(const float* __restrict__ x, const float* __restrict__ ln_w,
                 const float* __restrict__ ln_b, const float* __restrict__ w_qkv,
                 const float* __restrict__ w_out, const int* __restrict__ sid,
                 __hip_bfloat16* __restrict__ hbuf, __hip_bfloat16* __restrict__ wqkvT,
                 __hip_bfloat16* __restrict__ woutT, int* __restrict__ segstart,
                 int* __restrict__ segend) {
  __shared__ __align__(16) char smem[8448];
  const int blk = blockIdx.x;
  const int tid = threadIdx.x;

  if (blk < 4096) {
    // transpose+cast
    float (*tile)[33] = reinterpret_cast<float(*)[33]>(smem);
    const float* src;  __hip_bfloat16* dst;  int R, C, bx, by;
    if (blk < 3072) { src = w_qkv; dst = wqkvT; R = 1024; C = 3072; bx = blk % 96; by = blk / 96; }
    else            { src = w_out; dst = woutT; R = 1024; C = 1024; bx = (blk - 3072) & 31; by = (blk - 3072) >> 5; }
    const int c0 = bx * 32, r0 = by * 32;
    const int xx = tid & 31, yy = tid >> 5;   // 32 x 8
    #pragma unroll
    for (int j = 0; j < 32; j += 8)
      tile[yy + j][xx] = src[(size_t)(r0 + yy + j) * C + c0 + xx];
    __syncthreads();
    #pragma unroll
    for (int j = 0; j < 32; j += 8)
      dst[(size_t)(c0 + yy + j) * R + r0 + xx] = __float2bfloat16(tile[xx][yy + j]);
  } else if (blk < 6144) {
    // LayerNorm, wave per token
    const int lane = tid & 63;
    const int t = (blk - 4096) * 4 + (tid >> 6);
    const float4* xr = reinterpret_cast<const float4*>(x) + (size_t)t * 256;
    float4 v[4];
    float s = 0.f, ss = 0.f;
    #pragma unroll
    for (int i = 0; i < 4; i++) {
      v[i] = xr[lane + i * 64];
      s  += (v[i].x + v[i].y) + (v[i].z + v[i].w);
      ss += (v[i].x*v[i].x + v[i].y*v[i].y) + (v[i].z*v[i].z + v[i].w*v[i].w);
    }
    #pragma unroll
    for (int off = 1; off < 64; off <<= 1) {
      s  += __shfl_xor(s, off);
      ss += __shfl_xor(ss, off);
    }
    const float mu = s * (1.f / 1024);
    const float rs = rsqrtf(ss * (1.f / 1024) - mu * mu + 1e-5f);
    const float4* wr = reinterpret_cast<const float4*>(ln_w);
    const float4* br = reinterpret_cast<const float4*>(ln_b);
    ushort4* hr = reinterpret_cast<ushort4*>(hbuf) + (size_t)t * 256;
    #pragma unroll
    for (int i = 0; i < 4; i++) {
      const float4 wv = wr[lane + i * 64];
      const float4 bv = br[lane + i * 64];
      ushort4 o;
      o.x = f2bf_bits((v[i].x - mu) * rs * wv.x + bv.x);
      o.y = f2bf_bits((v[i].y - mu) * rs * wv.y + bv.y);
      o.z = f2bf_bits((v[i].z - mu) * rs * wv.z + bv.z);
      o.w = f2bf_bits((v[i].w - mu) * rs * wv.w + bv.w);
      hr[lane + i * 64] = o;
    }
  } else {
    // segment bounds (LDS-cached row)
    int* srow = reinterpret_cast<int*>(smem);
    const int sblk = blk - 6144;            // 0..31, 8 per batch
    const int b = sblk >> 3;
    const int* row = sid + (size_t)b * LSEQ;
    #pragma unroll
    for (int i = 0; i < 8; i++) srow[tid + i * 256] = row[tid + i * 256];
    __syncthreads();
    const int l = (sblk & 7) * 256 + tid;
    const int v = srow[l];
    int lo = 0, hi = l;
    while (lo < hi) { int mid = (lo + hi) >> 1; if (srow[mid] < v) lo = mid + 1; else hi = mid; }
    const int i = b * LSEQ + l;
    segstart[i] = lo;
    lo = l + 1; hi = LSEQ;
    while (lo < hi) { int mid = (lo + hi) >> 1; if (srow[mid] <= v) lo = mid + 1; else hi = mid; }
    segend[i] = lo;
  }
}

// ---------------------------------------------------------------- bf16 GEMM, Bt layout
// A: bf16 [M][K] row-major, Bt: bf16 [N][K] (B transposed), C: OutT [M][N]
// BK=64, XOR-swizzled LDS (conflict-free); 4 blocks/CU for barrier-drain overlap.
template <typename OutT>
__global__ __launch_bounds__(256, 4)
void gemm_bt(const __hip_bfloat16* __restrict__ A, const __hip_bfloat16* __restrict__ Bt,
             OutT* __restrict__ C, int M, int N, int K) {
  const int tid  = threadIdx.x;
  const int lane = tid & 63;
  const int wave = tid >> 6;
  const int bm = blockIdx.y * 128;
  const int bn = blockIdx.x * 128;
  const int wm = (wave & 1) * 64;
  const int wn = (wave >> 1) * 64;
  const int quad = lane >> 4;
  const int l16  = lane & 15;

  __shared__ __align__(16) __hip_bfloat16 As[128 * 64];
  __shared__ __align__(16) __hip_bfloat16 Bs[128 * 64];

  floatx4 acc[4][4];
  #pragma unroll
  for (int i = 0; i < 4; i++)
    #pragma unroll
    for (int j = 0; j < 4; j++) {
      floatx4 z = {0.f, 0.f, 0.f, 0.f};
      acc[i][j] = z;
    }

  const int srow = tid >> 3;
  const int sq   = tid & 7;
  const int sc8  = (sq ^ (srow & 7)) * 8;
  const __hip_bfloat16* Ab = A  + (size_t)(bm + srow) * K + sc8;
  const __hip_bfloat16* Bb = Bt + (size_t)(bn + srow) * K + sc8;

  const int axr = l16 & 7;

  for (int k0 = 0; k0 < K; k0 += 64) {
    __syncthreads();
    #pragma unroll
    for (int p = 0; p < 4; p++) {
      gld_lds16(Ab + (size_t)(p * 32) * K + k0, (char*)As + p * 4096 + tid * 16);
      gld_lds16(Bb + (size_t)(p * 32) * K + k0, (char*)Bs + p * 4096 + tid * 16);
    }
    __syncthreads();
    #pragma unroll
    for (int s0 = 0; s0 < 2; s0++) {
      const int qo = ((s0 * 4 + quad) ^ axr) * 8;
      short8 af[4], bfr[4];
      #pragma unroll
      for (int i = 0; i < 4; i++)
        af[i] = *reinterpret_cast<const short8*>(As + (wm + i * 16 + l16) * 64 + qo);
      #pragma unroll
      for (int j = 0; j < 4; j++)
        bfr[j] = *reinterpret_cast<const short8*>(Bs + (wn + j * 16 + l16) * 64 + qo);
      #pragma unroll
      for (int i = 0; i < 4; i++)
        #pragma unroll
        for (int j = 0; j < 4; j++)
          acc[i][j] = __builtin_amdgcn_mfma_f32_16x16x32_bf16(af[i], bfr[j], acc[i][j], 0, 0, 0);
    }
  }

  #pragma unroll
  for (int i = 0; i < 4; i++)
    #pragma unroll
    for (int j = 0; j < 4; j++) {
      const int row0 = bm + wm + i * 16 + quad * 4;
      const int col  = bn + wn + j * 16 + l16;
      #pragma unroll
      for (int r = 0; r < 4; r++) {
        if constexpr (std::is_same<OutT, __hip_bfloat16>::value)
          C[(size_t)(row0 + r) * N + col] = __float2bfloat16(acc[i][j][r]);
        else
          C[(size_t)(row0 + r) * N + col] = acc[i][j][r];
      }
    }
}

// ---------------------------------------------------------------- fused rope + vtrans
// blocks [0,2048): QK-LN + RoPE, wave per token (Q pre-scaled by 1/8)
// blocks [2048,4096): V transpose per (b,h) tile, DMA + XOR swizzle
__global__ __launch_bounds__(256)
void ropevt_kernel(const unsigned short* __restrict__ qkv, const float* __restrict__ qw,
                   const float* __restrict__ kw, unsigned short* __restrict__ qT,
                   unsigned short* __restrict__ kT, unsigned short* __restrict__ vT) {
  __shared__ __align__(16) unsigned short T[64 * 64];
  const int blk = blockIdx.x;
  const int tid = threadIdx.x;

  if (blk < 2048) {
    const int lane = tid & 63;
    const int t = blk * 4 + (tid >> 6);
    const int b = t >> 11, l = t & 2047;
    const unsigned short* row = qkv + (size_t)t * K3;
    const int hh = lane >> 2;
    const int jb = (lane & 3) * 8;
    const int base = hh * 64 + jb;

    const short8 qa_u = *reinterpret_cast<const short8*>(row + base);
    const short8 qb_u = *reinterpret_cast<const short8*>(row + base + 32);
    const short8 ka_u = *reinterpret_cast<const short8*>(row + 1024 + base);
    const short8 kb_u = *reinterpret_cast<const short8*>(row + 1024 + base + 32);

    float qa[8], qb[8], ka[8], kb[8];
    float s_q = 0.f, ss_q = 0.f, s_k = 0.f, ss_k = 0.f;
    #pragma unroll
    for (int e = 0; e < 8; e++) {
      qa[e] = bf2f((unsigned short)qa_u[e]); qb[e] = bf2f((unsigned short)qb_u[e]);
      ka[e] = bf2f((unsigned short)ka_u[e]); kb[e] = bf2f((unsigned short)kb_u[e]);
      s_q  += qa[e] + qb[e];  ss_q += qa[e]*qa[e] + qb[e]*qb[e];
      s_k  += ka[e] + kb[e];  ss_k += ka[e]*ka[e] + kb[e]*kb[e];
    }
    #pragma unroll
    for (int off = 1; off < 64; off <<= 1) {
      s_q  += __shfl_xor(s_q, off);  ss_q += __shfl_xor(ss_q, off);
      s_k  += __shfl_xor(s_k, off);  ss_k += __shfl_xor(ss_k, off);
    }
    const float qmu = s_q * (1.f/1024);
    const float qrs = rsqrtf(ss_q * (1.f/1024) - qmu*qmu + 1e-5f);
    const float kmu = s_k * (1.f/1024);
    const float krs = rsqrtf(ss_k * (1.f/1024) - kmu*kmu + 1e-5f);

    const int j0 = lane & 31;
    const float invf = __expf(-(float)j0 * 0.28782313662425575f);   // ln(1e4)/32
    float tsin, tcos;
    sincosf((float)l * invf, &tsin, &tcos);

    const float4 wq0 = *reinterpret_cast<const float4*>(qw + base);
    const float4 wq1 = *reinterpret_cast<const float4*>(qw + base + 4);
    const float4 wq2 = *reinterpret_cast<const float4*>(qw + base + 32);
    const float4 wq3 = *reinterpret_cast<const float4*>(qw + base + 36);
    const float4 wk0 = *reinterpret_cast<const float4*>(kw + base);
    const float4 wk1 = *reinterpret_cast<const float4*>(kw + base + 4);
    const float4 wk2 = *reinterpret_cast<const float4*>(kw + base + 32);
    const float4 wk3 = *reinterpret_cast<const float4*>(kw + base + 36);
    const float wqa[8] = {wq0.x,wq0.y,wq0.z,wq0.w, wq1.x,wq1.y,wq1.z,wq1.w};
    const float wqb[8] = {wq2.x,wq2.y,wq2.z,wq2.w, wq3.x,wq3.y,wq3.z,wq3.w};
    const float wka[8] = {wk0.x,wk0.y,wk0.z,wk0.w, wk1.x,wk1.y,wk1.z,wk1.w};
    const float wkb[8] = {wk2.x,wk2.y,wk2.z,wk2.w, wk3.x,wk3.y,wk3.z,wk3.w};

    short8 oqa, oqb, oka, okb;
    #pragma unroll
    for (int e = 0; e < 8; e++) {
      const int j = jb + e;
      const float c  = __shfl(tcos, j);
      const float sn = __shfl(tsin, j);
      const float qn1 = (qa[e] - qmu) * qrs * wqa[e];
      const float qn2 = (qb[e] - qmu) * qrs * wqb[e];
      const float kn1 = (ka[e] - kmu) * krs * wka[e];
      const float kn2 = (kb[e] - kmu) * krs * wkb[e];
      oqa[e] = (short)f2bf_bits((qn1 * c - qn2 * sn) * 0.125f);
      oqb[e] = (short)f2bf_bits((qn2 * c + qn1 * sn) * 0.125f);
      oka[e] = (short)f2bf_bits(kn1 * c - kn2 * sn);
      okb[e] = (short)f2bf_bits(kn2 * c + kn1 * sn);
    }
    const size_t ob = ((size_t)(b * NH + hh) * LSEQ + l) * DH + jb;
    *reinterpret_cast<short8*>(qT + ob)      = oqa;
    *reinterpret_cast<short8*>(qT + ob + 32) = oqb;
    *reinterpret_cast<short8*>(kT + ob)      = oka;
    *reinterpret_cast<short8*>(kT + ob + 32) = okb;
  } else {
    const int blkv = blk - 2048;
    const int l0 = (blkv & 31) * 64;
    const int bh = blkv >> 5;
    const int b = bh >> 4, h = bh & 15;
    const int sr = tid >> 3, scc = tid & 7;
    const int r1 = sr + 32;
    gld_lds16(qkv + (size_t)(b * LSEQ + l0 + sr) * K3 + 2048 + h * 64 + ((scc ^ ((sr >> 3) & 7)) * 8),
              (char*)T + tid * 16);
    gld_lds16(qkv + (size_t)(b * LSEQ + l0 + r1) * K3 + 2048 + h * 64 + ((scc ^ ((r1 >> 3) & 7)) * 8),
              (char*)T + 4096 + tid * 16);
    __syncthreads();
    #pragma unroll
    for (int it = 0; it < 2; it++) {
      const int cid = tid + it * 256;
      const int dh = cid >> 3, c = (cid & 7) * 8;
      const int sl = (dh >> 3) ^ ((c >> 3) & 7);
      short8 o;
      #pragma unroll
      for (int e = 0; e < 8; e++)
        o[e] = (short)T[(c + e) * 64 + sl * 8 + (dh & 7)];
      *reinterpret_cast<short8*>(vT + ((size_t)bh * DH + dh) * LSEQ + l0 + c) = o;
    }
  }
}

// ---------------------------------------------------------------- MFMA flash attention
// S^T-form softmax + DMA-staged, XOR-swizzled K/V tiles.
__global__ __launch_bounds__(256)
void attn_mfma(const unsigned short* __restrict__ qT, const unsigned short* __restrict__ kT,
               const unsigned short* __restrict__ vT, const int* __restrict__ segs,
               const int* __restrict__ sege, unsigned short* __restrict__ ctx) {
  const int tid  = threadIdx.x;
  const int lane = tid & 63, w = tid >> 6;
  const int quad = lane >> 4, l16 = lane & 15;
  const int qbase = blockIdx.x * 64;
  const int h = blockIdx.y, b = blockIdx.z;
  const int qy = qbase + w * 16 + l16;
  const size_t bh = (size_t)(b * NH + h);
  const unsigned short* Kg = kT + bh * LSEQ * DH;
  const unsigned short* Vg = vT + bh * DH * LSEQ;

  __shared__ __align__(16) unsigned short Ks[64 * 64];
  __shared__ __align__(16) unsigned short Vs[64 * 64];
  __shared__ __align__(16) unsigned short Ps[4][16 * 72];

  const unsigned short* Qrow = qT + (bh * LSEQ + qy) * DH;
  const short8 qf0 = *reinterpret_cast<const short8*>(Qrow + quad * 8);
  const short8 qf1 = *reinterpret_cast<const short8*>(Qrow + 32 + quad * 8);

  const int st = segs[b * LSEQ + qy];
  const int en = sege[b * LSEQ + qy];
  const unsigned span = (unsigned)(en - st);
  const int kmin = segs[b * LSEQ + qbase] & ~63;
  const int kmax = sege[b * LSEQ + qbase + 63];
  const int wmin = segs[b * LSEQ + qbase + w * 16];
  const int wmax = sege[b * LSEQ + qbase + w * 16 + 15];

  floatx4 acc[4];
  #pragma unroll
  for (int dt = 0; dt < 4; dt++) { floatx4 z = {0.f,0.f,0.f,0.f}; acc[dt] = z; }
  float m = -1e30f, lsum = 0.f;

  const int sr  = tid >> 3, scc = tid & 7;
  const int r1  = sr + 32;
  const int sx0 = (scc ^ ((sr >> 3) & 7)) * 8;
  const int sx1 = (scc ^ ((r1 >> 3) & 7)) * 8;
  const int fx  = l16 >> 3;

  for (int kk = kmin; kk < kmax; kk += 64) {
    __syncthreads();
    gld_lds16(Kg + (size_t)(kk + sr) * DH + sx0, (char*)Ks + tid * 16);
    gld_lds16(Kg + (size_t)(kk + r1) * DH + sx1, (char*)Ks + 4096 + tid * 16);
    gld_lds16(Vg + (size_t)sr * LSEQ + kk + sx0, (char*)Vs + tid * 16);
    gld_lds16(Vg + (size_t)r1 * LSEQ + kk + sx1, (char*)Vs + 4096 + tid * 16);
    __syncthreads();

    if (kk + 64 <= wmin || kk >= wmax) continue;

    floatx4 sc[4];
    #pragma unroll
    for (int t = 0; t < 4; t++) {
      const int row = t * 16 + l16;
      const int kx = (2 * t + fx) & 7;
      const short8 kf0 = *reinterpret_cast<const short8*>(Ks + row * 64 + ((quad ^ kx) * 8));
      const short8 kf1 = *reinterpret_cast<const short8*>(Ks + row * 64 + (((quad + 4) ^ kx) * 8));
      floatx4 z = {0.f,0.f,0.f,0.f};
      sc[t] = __builtin_amdgcn_mfma_f32_16x16x32_bf16(kf0, qf0, z, 0, 0, 0);
      sc[t] = __builtin_amdgcn_mfma_f32_16x16x32_bf16(kf1, qf1, sc[t], 0, 0, 0);
    }

    float vm = -1e30f;
    #pragma unroll
    for (int t = 0; t < 4; t++) {
      const int k0 = kk + t * 16 + quad * 4;
      #pragma unroll
      for (int r = 0; r < 4; r++) {
        const bool ok = (unsigned)(k0 + r - st) < span;
        sc[t][r] = ok ? sc[t][r] : -1e30f;
        vm = fmaxf(vm, sc[t][r]);
      }
    }
    vm = fmaxf(vm, __shfl_xor(vm, 16));
    vm = fmaxf(vm, __shfl_xor(vm, 32));
    const float mn = fmaxf(m, vm);
    const float alpha = __expf(m - mn);
    m = mn;

    float rs = 0.f;
    #pragma unroll
    for (int t = 0; t < 4; t++) {
      float p0 = (sc[t][0] > -1e29f) ? __expf(sc[t][0] - mn) : 0.f;
      float p1 = (sc[t][1] > -1e29f) ? __expf(sc[t][1] - mn) : 0.f;
      float p2 = (sc[t][2] > -1e29f) ? __expf(sc[t][2] - mn) : 0.f;
      float p3 = (sc[t][3] > -1e29f) ? __expf(sc[t][3] - mn) : 0.f;
      rs += (p0 + p1) + (p2 + p3);
      uint2 pk;
      pk.x = pack_bf16(p0, p1);
      pk.y = pack_bf16(p2, p3);
      *reinterpret_cast<uint2*>(&Ps[w][l16 * 72 + t * 16 + quad * 4]) = pk;
    }
    rs += __shfl_xor(rs, 16);
    rs += __shfl_xor(rs, 32);
    lsum = lsum * alpha + rs;

    const short8 pf0 = *reinterpret_cast<const short8*>(&Ps[w][l16 * 72 + quad * 8]);
    const short8 pf1 = *reinterpret_cast<const short8*>(&Ps[w][l16 * 72 + 32 + quad * 8]);

    #pragma unroll
    for (int dt = 0; dt < 4; dt++) {
      #pragma unroll
      for (int r = 0; r < 4; r++) acc[dt][r] *= alpha;
      const int row = dt * 16 + l16;
      const int vx = (2 * dt + fx) & 7;
      const short8 vf0 = *reinterpret_cast<const short8*>(Vs + row * 64 + ((quad ^ vx) * 8));
      const short8 vf1 = *reinterpret_cast<const short8*>(Vs + row * 64 + (((quad + 4) ^ vx) * 8));
      acc[dt] = __builtin_amdgcn_mfma_f32_16x16x32_bf16(vf0, pf0, acc[dt], 0, 0, 0);
      acc[dt] = __builtin_amdgcn_mfma_f32_16x16x32_bf16(vf1, pf1, acc[dt], 0, 0, 0);
    }
  }

  const float inv = (lsum > 0.f) ? 1.f / lsum : 0.f;
  unsigned short* orow = ctx + ((size_t)(b * LSEQ + qy)) * D_MODEL + h * DH;
  #pragma unroll
  for (int dt = 0; dt < 4; dt++) {
    uint2 o;
    o.x = pack_bf16(acc[dt][0] * inv, acc[dt][1] * inv);
    o.y = pack_bf16(acc[dt][2] * inv, acc[dt][3] * inv);
    *reinterpret_cast<uint2*>(orow + dt * 16 + quad * 4) = o;
  }
}

// ---------------------------------------------------------------- launch
extern "C" void kernel_launch(void* const* d_in, const int* in_sizes, int n_in,
                              void* d_out, int out_size, void* d_ws, size_t ws_size,
                              hipStream_t stream) {
  const float* x      = (const float*)d_in[0];
  const int*   sid    = (const int*)d_in[1];
  const float* ln_w   = (const float*)d_in[2];
  const float* ln_b   = (const float*)d_in[3];
  const float* w_qkv  = (const float*)d_in[4];
  const float* q_ln_w = (const float*)d_in[5];
  const float* k_ln_w = (const float*)d_in[6];
  const float* w_out  = (const float*)d_in[7];
  float* out = (float*)d_out;
  char* ws = (char*)d_ws;

  constexpr size_t OFF_WQKVT = 0;                        //  6,291,456
  constexpr size_t OFF_WOUTT = 6291456;                  //  2,097,152
  constexpr size_t OFF_H     = 8388608;                  // 16,777,216
  constexpr size_t OFF_QKV   = 25165824;                 // 50,331,648 (bf16)
  constexpr size_t OFF_QT    = 75497472;                 // 16,777,216
  constexpr size_t OFF_KT    = 92274688;                 // 16,777,216
  constexpr size_t OFF_VT    = 109051904;                // 16,777,216
  constexpr size_t OFF_CTX   = 125829120;                // 16,777,216
  constexpr size_t OFF_SEGS  = 142606336;                // 32,768
  constexpr size_t OFF_SEGE  = 142639104;                // 32,768

  __hip_bfloat16* wqkvT = (__hip_bfloat16*)(ws + OFF_WQKVT);
  __hip_bfloat16* woutT = (__hip_bfloat16*)(ws + OFF_WOUTT);
  __hip_bfloat16* hbuf  = (__hip_bfloat16*)(ws + OFF_H);
  __hip_bfloat16* qkvb  = (__hip_bfloat16*)(ws + OFF_QKV);
  unsigned short* qTb   = (unsigned short*)(ws + OFF_QT);
  unsigned short* kTb   = (unsigned short*)(ws + OFF_KT);
  unsigned short* vTb   = (unsigned short*)(ws + OFF_VT);
  unsigned short* ctx   = (unsigned short*)(ws + OFF_CTX);
  int*            segst = (int*)(ws + OFF_SEGS);
  int*            segen = (int*)(ws + OFF_SEGE);

  prep_kernel<<<6176, 256, 0, stream>>>(x, ln_w, ln_b, w_qkv, w_out, sid,
                                        hbuf, wqkvT, woutT, segst, segen);
  gemm_bt<__hip_bfloat16><<<dim3(K3 / 128, NTOK / 128), 256, 0, stream>>>(
      hbuf, wqkvT, qkvb, NTOK, K3, 1024);
  ropevt_kernel<<<4096, 256, 0, stream>>>((const unsigned short*)qkvb, q_ln_w, k_ln_w,
                                          qTb, kTb, vTb);
  attn_mfma<<<dim3(LSEQ / 64, NH, BATCH), 256, 0, stream>>>(qTb, kTb, vTb, segst, segen, ctx);
  gemm_bt<float><<<dim3(D_MODEL / 128, NTOK / 128), 256, 0, stream>>>(
      (const __hip_bfloat16*)ctx, woutT, out, NTOK, D_MODEL, 1024);
}

// Round 9
// 247.924 us; speedup vs baseline: 1.3716x; 1.0030x over previous
//
#include <hip/hip_runtime.h>
#include <hip/hip_bf16.h>
#include <cstdint>
#include <cstddef>
#include <type_traits>

#define D_MODEL 1024
#define NH      16
#define DH      64
#define LSEQ    2048
#define BATCH   4
#define NTOK    8192      // BATCH * LSEQ
#define K3      3072

typedef __attribute__((ext_vector_type(8))) short  short8;
typedef __attribute__((ext_vector_type(4))) float  floatx4;

__device__ __forceinline__ unsigned short f2bf_bits(float f) {
  __hip_bfloat16 h = __float2bfloat16(f);
  return __builtin_bit_cast(unsigned short, h);
}
__device__ __forceinline__ float bf2f(unsigned short u) {
  return __bfloat162float(__builtin_bit_cast(__hip_bfloat16, u));
}
__device__ __forceinline__ unsigned int pack_bf16(float lo, float hi) {
  return (unsigned int)f2bf_bits(lo) | ((unsigned int)f2bf_bits(hi) << 16);
}

__device__ __forceinline__ void gld_lds16(const void* g, void* l) {
  __builtin_amdgcn_global_load_lds(
      (const __attribute__((address_space(1))) void*)g,
      (__attribute__((address_space(3))) void*)l,
      16, 0, 0);
}

// ---------------------------------------------------------------- fused prologue
// blocks [0,3072): transpose+cast w_qkv [1024][3072] -> wqkvT [3072][1024]
// blocks [3072,4096): transpose+cast w_out [1024][1024] -> woutT
// blocks [4096,6144): LayerNorm(x) -> hbuf (4 tokens/block, wave per token)
// blocks [6144,6176): segment bounds
__global__ __launch_bounds__(256)
void prep_kernel(const float* __restrict__ x, const float* __restrict__ ln_w,
                 const float* __restrict__ ln_b, const float* __restrict__ w_qkv,
                 const float* __restrict__ w_out, const int* __restrict__ sid,
                 __hip_bfloat16* __restrict__ hbuf, __hip_bfloat16* __restrict__ wqkvT,
                 __hip_bfloat16* __restrict__ woutT, int* __restrict__ segstart,
                 int* __restrict__ segend) {
  __shared__ __align__(16) char smem[8448];
  const int blk = blockIdx.x;
  const int tid = threadIdx.x;

  if (blk < 4096) {
    float (*tile)[33] = reinterpret_cast<float(*)[33]>(smem);
    const float* src;  __hip_bfloat16* dst;  int R, C, bx, by;
    if (blk < 3072) { src = w_qkv; dst = wqkvT; R = 1024; C = 3072; bx = blk % 96; by = blk / 96; }
    else            { src = w_out; dst = woutT; R = 1024; C = 1024; bx = (blk - 3072) & 31; by = (blk - 3072) >> 5; }
    const int c0 = bx * 32, r0 = by * 32;
    const int xx = tid & 31, yy = tid >> 5;   // 32 x 8
    #pragma unroll
    for (int j = 0; j < 32; j += 8)
      tile[yy + j][xx] = src[(size_t)(r0 + yy + j) * C + c0 + xx];
    __syncthreads();
    #pragma unroll
    for (int j = 0; j < 32; j += 8)
      dst[(size_t)(c0 + yy + j) * R + r0 + xx] = __float2bfloat16(tile[xx][yy + j]);
  } else if (blk < 6144) {
    const int lane = tid & 63;
    const int t = (blk - 4096) * 4 + (tid >> 6);
    const float4* xr = reinterpret_cast<const float4*>(x) + (size_t)t * 256;
    float4 v[4];
    float s = 0.f, ss = 0.f;
    #pragma unroll
    for (int i = 0; i < 4; i++) {
      v[i] = xr[lane + i * 64];
      s  += (v[i].x + v[i].y) + (v[i].z + v[i].w);
      ss += (v[i].x*v[i].x + v[i].y*v[i].y) + (v[i].z*v[i].z + v[i].w*v[i].w);
    }
    #pragma unroll
    for (int off = 1; off < 64; off <<= 1) {
      s  += __shfl_xor(s, off);
      ss += __shfl_xor(ss, off);
    }
    const float mu = s * (1.f / 1024);
    const float rs = rsqrtf(ss * (1.f / 1024) - mu * mu + 1e-5f);
    const float4* wr = reinterpret_cast<const float4*>(ln_w);
    const float4* br = reinterpret_cast<const float4*>(ln_b);
    ushort4* hr = reinterpret_cast<ushort4*>(hbuf) + (size_t)t * 256;
    #pragma unroll
    for (int i = 0; i < 4; i++) {
      const float4 wv = wr[lane + i * 64];
      const float4 bv = br[lane + i * 64];
      ushort4 o;
      o.x = f2bf_bits((v[i].x - mu) * rs * wv.x + bv.x);
      o.y = f2bf_bits((v[i].y - mu) * rs * wv.y + bv.y);
      o.z = f2bf_bits((v[i].z - mu) * rs * wv.z + bv.z);
      o.w = f2bf_bits((v[i].w - mu) * rs * wv.w + bv.w);
      hr[lane + i * 64] = o;
    }
  } else {
    int* srow = reinterpret_cast<int*>(smem);
    const int sblk = blk - 6144;            // 0..31, 8 per batch
    const int b = sblk >> 3;
    const int* row = sid + (size_t)b * LSEQ;
    #pragma unroll
    for (int i = 0; i < 8; i++) srow[tid + i * 256] = row[tid + i * 256];
    __syncthreads();
    const int l = (sblk & 7) * 256 + tid;
    const int v = srow[l];
    int lo = 0, hi = l;
    while (lo < hi) { int mid = (lo + hi) >> 1; if (srow[mid] < v) lo = mid + 1; else hi = mid; }
    const int i = b * LSEQ + l;
    segstart[i] = lo;
    lo = l + 1; hi = LSEQ;
    while (lo < hi) { int mid = (lo + hi) >> 1; if (srow[mid] <= v) lo = mid + 1; else hi = mid; }
    segend[i] = lo;
  }
}

// ---------------------------------------------------------------- bf16 GEMM, Bt layout
// BK=64, XOR-swizzled LDS (conflict-free). launch_bounds(256,2): measured best.
template <typename OutT>
__global__ __launch_bounds__(256, 2)
void gemm_bt(const __hip_bfloat16* __restrict__ A, const __hip_bfloat16* __restrict__ Bt,
             OutT* __restrict__ C, int M, int N, int K) {
  const int tid  = threadIdx.x;
  const int lane = tid & 63;
  const int wave = tid >> 6;
  const int bm = blockIdx.y * 128;
  const int bn = blockIdx.x * 128;
  const int wm = (wave & 1) * 64;
  const int wn = (wave >> 1) * 64;
  const int quad = lane >> 4;
  const int l16  = lane & 15;

  __shared__ __align__(16) __hip_bfloat16 As[128 * 64];
  __shared__ __align__(16) __hip_bfloat16 Bs[128 * 64];

  floatx4 acc[4][4];
  #pragma unroll
  for (int i = 0; i < 4; i++)
    #pragma unroll
    for (int j = 0; j < 4; j++) {
      floatx4 z = {0.f, 0.f, 0.f, 0.f};
      acc[i][j] = z;
    }

  const int srow = tid >> 3;
  const int sq   = tid & 7;
  const int sc8  = (sq ^ (srow & 7)) * 8;
  const __hip_bfloat16* Ab = A  + (size_t)(bm + srow) * K + sc8;
  const __hip_bfloat16* Bb = Bt + (size_t)(bn + srow) * K + sc8;

  const int axr = l16 & 7;

  for (int k0 = 0; k0 < K; k0 += 64) {
    __syncthreads();
    #pragma unroll
    for (int p = 0; p < 4; p++) {
      gld_lds16(Ab + (size_t)(p * 32) * K + k0, (char*)As + p * 4096 + tid * 16);
      gld_lds16(Bb + (size_t)(p * 32) * K + k0, (char*)Bs + p * 4096 + tid * 16);
    }
    __syncthreads();
    #pragma unroll
    for (int s0 = 0; s0 < 2; s0++) {
      const int qo = ((s0 * 4 + quad) ^ axr) * 8;
      short8 af[4], bfr[4];
      #pragma unroll
      for (int i = 0; i < 4; i++)
        af[i] = *reinterpret_cast<const short8*>(As + (wm + i * 16 + l16) * 64 + qo);
      #pragma unroll
      for (int j = 0; j < 4; j++)
        bfr[j] = *reinterpret_cast<const short8*>(Bs + (wn + j * 16 + l16) * 64 + qo);
      #pragma unroll
      for (int i = 0; i < 4; i++)
        #pragma unroll
        for (int j = 0; j < 4; j++)
          acc[i][j] = __builtin_amdgcn_mfma_f32_16x16x32_bf16(af[i], bfr[j], acc[i][j], 0, 0, 0);
    }
  }

  #pragma unroll
  for (int i = 0; i < 4; i++)
    #pragma unroll
    for (int j = 0; j < 4; j++) {
      const int row0 = bm + wm + i * 16 + quad * 4;
      const int col  = bn + wn + j * 16 + l16;
      #pragma unroll
      for (int r = 0; r < 4; r++) {
        if constexpr (std::is_same<OutT, __hip_bfloat16>::value)
          C[(size_t)(row0 + r) * N + col] = __float2bfloat16(acc[i][j][r]);
        else
          C[(size_t)(row0 + r) * N + col] = acc[i][j][r];
      }
    }
}

// ---------------------------------------------------------------- fused rope + vtrans
__global__ __launch_bounds__(256)
void ropevt_kernel(const unsigned short* __restrict__ qkv, const float* __restrict__ qw,
                   const float* __restrict__ kw, unsigned short* __restrict__ qT,
                   unsigned short* __restrict__ kT, unsigned short* __restrict__ vT) {
  __shared__ __align__(16) unsigned short T[64 * 64];
  const int blk = blockIdx.x;
  const int tid = threadIdx.x;

  if (blk < 2048) {
    const int lane = tid & 63;
    const int t = blk * 4 + (tid >> 6);
    const int b = t >> 11, l = t & 2047;
    const unsigned short* row = qkv + (size_t)t * K3;
    const int hh = lane >> 2;
    const int jb = (lane & 3) * 8;
    const int base = hh * 64 + jb;

    const short8 qa_u = *reinterpret_cast<const short8*>(row + base);
    const short8 qb_u = *reinterpret_cast<const short8*>(row + base + 32);
    const short8 ka_u = *reinterpret_cast<const short8*>(row + 1024 + base);
    const short8 kb_u = *reinterpret_cast<const short8*>(row + 1024 + base + 32);

    float qa[8], qb[8], ka[8], kb[8];
    float s_q = 0.f, ss_q = 0.f, s_k = 0.f, ss_k = 0.f;
    #pragma unroll
    for (int e = 0; e < 8; e++) {
      qa[e] = bf2f((unsigned short)qa_u[e]); qb[e] = bf2f((unsigned short)qb_u[e]);
      ka[e] = bf2f((unsigned short)ka_u[e]); kb[e] = bf2f((unsigned short)kb_u[e]);
      s_q  += qa[e] + qb[e];  ss_q += qa[e]*qa[e] + qb[e]*qb[e];
      s_k  += ka[e] + kb[e];  ss_k += ka[e]*ka[e] + kb[e]*kb[e];
    }
    #pragma unroll
    for (int off = 1; off < 64; off <<= 1) {
      s_q  += __shfl_xor(s_q, off);  ss_q += __shfl_xor(ss_q, off);
      s_k  += __shfl_xor(s_k, off);  ss_k += __shfl_xor(ss_k, off);
    }
    const float qmu = s_q * (1.f/1024);
    const float qrs = rsqrtf(ss_q * (1.f/1024) - qmu*qmu + 1e-5f);
    const float kmu = s_k * (1.f/1024);
    const float krs = rsqrtf(ss_k * (1.f/1024) - kmu*kmu + 1e-5f);

    const int j0 = lane & 31;
    const float invf = __expf(-(float)j0 * 0.28782313662425575f);   // ln(1e4)/32
    float tsin, tcos;
    sincosf((float)l * invf, &tsin, &tcos);

    const float4 wq0 = *reinterpret_cast<const float4*>(qw + base);
    const float4 wq1 = *reinterpret_cast<const float4*>(qw + base + 4);
    const float4 wq2 = *reinterpret_cast<const float4*>(qw + base + 32);
    const float4 wq3 = *reinterpret_cast<const float4*>(qw + base + 36);
    const float4 wk0 = *reinterpret_cast<const float4*>(kw + base);
    const float4 wk1 = *reinterpret_cast<const float4*>(kw + base + 4);
    const float4 wk2 = *reinterpret_cast<const float4*>(kw + base + 32);
    const float4 wk3 = *reinterpret_cast<const float4*>(kw + base + 36);
    const float wqa[8] = {wq0.x,wq0.y,wq0.z,wq0.w, wq1.x,wq1.y,wq1.z,wq1.w};
    const float wqb[8] = {wq2.x,wq2.y,wq2.z,wq2.w, wq3.x,wq3.y,wq3.z,wq3.w};
    const float wka[8] = {wk0.x,wk0.y,wk0.z,wk0.w, wk1.x,wk1.y,wk1.z,wk1.w};
    const float wkb[8] = {wk2.x,wk2.y,wk2.z,wk2.w, wk3.x,wk3.y,wk3.z,wk3.w};

    short8 oqa, oqb, oka, okb;
    #pragma unroll
    for (int e = 0; e < 8; e++) {
      const int j = jb + e;
      const float c  = __shfl(tcos, j);
      const float sn = __shfl(tsin, j);
      const float qn1 = (qa[e] - qmu) * qrs * wqa[e];
      const float qn2 = (qb[e] - qmu) * qrs * wqb[e];
      const float kn1 = (ka[e] - kmu) * krs * wka[e];
      const float kn2 = (kb[e] - kmu) * krs * wkb[e];
      oqa[e] = (short)f2bf_bits((qn1 * c - qn2 * sn) * 0.125f);
      oqb[e] = (short)f2bf_bits((qn2 * c + qn1 * sn) * 0.125f);
      oka[e] = (short)f2bf_bits(kn1 * c - kn2 * sn);
      okb[e] = (short)f2bf_bits(kn2 * c + kn1 * sn);
    }
    const size_t ob = ((size_t)(b * NH + hh) * LSEQ + l) * DH + jb;
    *reinterpret_cast<short8*>(qT + ob)      = oqa;
    *reinterpret_cast<short8*>(qT + ob + 32) = oqb;
    *reinterpret_cast<short8*>(kT + ob)      = oka;
    *reinterpret_cast<short8*>(kT + ob + 32) = okb;
  } else {
    const int blkv = blk - 2048;
    const int l0 = (blkv & 31) * 64;
    const int bh = blkv >> 5;
    const int b = bh >> 4, h = bh & 15;
    const int sr = tid >> 3, scc = tid & 7;
    const int r1 = sr + 32;
    gld_lds16(qkv + (size_t)(b * LSEQ + l0 + sr) * K3 + 2048 + h * 64 + ((scc ^ ((sr >> 3) & 7)) * 8),
              (char*)T + tid * 16);
    gld_lds16(qkv + (size_t)(b * LSEQ + l0 + r1) * K3 + 2048 + h * 64 + ((scc ^ ((r1 >> 3) & 7)) * 8),
              (char*)T + 4096 + tid * 16);
    __syncthreads();
    #pragma unroll
    for (int it = 0; it < 2; it++) {
      const int cid = tid + it * 256;
      const int dh = cid >> 3, c = (cid & 7) * 8;
      const int sl = (dh >> 3) ^ ((c >> 3) & 7);
      short8 o;
      #pragma unroll
      for (int e = 0; e < 8; e++)
        o[e] = (short)T[(c + e) * 64 + sl * 8 + (dh & 7)];
      *reinterpret_cast<short8*>(vT + ((size_t)bh * DH + dh) * LSEQ + l0 + c) = o;
    }
  }
}

// ---------------------------------------------------------------- MFMA flash attention
// 128-query tile/block; each wave owns 32 queries (2 groups of 16).
// S^T-form softmax; manual staging into stride-72 padded LDS (bank-rotating).
__global__ __launch_bounds__(256)
void attn_mfma(const unsigned short* __restrict__ qT, const unsigned short* __restrict__ kT,
               const unsigned short* __restrict__ vT, const int* __restrict__ segs,
               const int* __restrict__ sege, unsigned short* __restrict__ ctx) {
  const int tid  = threadIdx.x;
  const int lane = tid & 63, w = tid >> 6;
  const int quad = lane >> 4, l16 = lane & 15;
  const int qbase = blockIdx.x * 128;
  const int h = blockIdx.y, b = blockIdx.z;
  const size_t bh = (size_t)(b * NH + h);
  const unsigned short* Kg = kT + bh * LSEQ * DH;
  const unsigned short* Vg = vT + bh * DH * LSEQ;

  __shared__ __align__(16) unsigned short Ks[64 * 72];
  __shared__ __align__(16) unsigned short Vs[64 * 72];
  __shared__ __align__(16) unsigned short Ps[4][32 * 72];

  short8 qf[2][2];
  int st[2], en[2];
  #pragma unroll
  for (int g = 0; g < 2; g++) {
    const int qy = qbase + w * 32 + g * 16 + l16;
    const unsigned short* Qrow = qT + (bh * LSEQ + qy) * DH;
    qf[g][0] = *reinterpret_cast<const short8*>(Qrow + quad * 8);
    qf[g][1] = *reinterpret_cast<const short8*>(Qrow + 32 + quad * 8);
    st[g] = segs[b * LSEQ + qy];
    en[g] = sege[b * LSEQ + qy];
  }

  const int kmin = segs[b * LSEQ + qbase] & ~63;
  const int kmax = sege[b * LSEQ + qbase + 127];
  const int wmin = segs[b * LSEQ + qbase + w * 32];
  const int wmax = sege[b * LSEQ + qbase + w * 32 + 31];
  int gmin[2], gmax[2];
  #pragma unroll
  for (int g = 0; g < 2; g++) {
    gmin[g] = segs[b * LSEQ + qbase + w * 32 + g * 16];
    gmax[g] = sege[b * LSEQ + qbase + w * 32 + g * 16 + 15];
  }

  floatx4 acc[2][4];
  #pragma unroll
  for (int g = 0; g < 2; g++)
    #pragma unroll
    for (int dt = 0; dt < 4; dt++) { floatx4 z = {0.f,0.f,0.f,0.f}; acc[g][dt] = z; }
  float m[2] = {-1e30f, -1e30f}, lsum[2] = {0.f, 0.f};

  const int r_ = tid >> 3, c_ = (tid & 7) * 8;

  for (int kk = kmin; kk < kmax; kk += 64) {
    __syncthreads();
    #pragma unroll
    for (int it = 0; it < 2; it++) {
      const int r = r_ + it * 32;
      *reinterpret_cast<short8*>(Ks + r * 72 + c_) =
          *reinterpret_cast<const short8*>(Kg + (size_t)(kk + r) * DH + c_);
      *reinterpret_cast<short8*>(Vs + r * 72 + c_) =
          *reinterpret_cast<const short8*>(Vg + (size_t)r * LSEQ + kk + c_);
    }
    __syncthreads();

    if (kk + 64 <= wmin || kk >= wmax) continue;   // tile outside this wave's 32-query span

    float alpha[2];
    bool act[2];
    #pragma unroll
    for (int g = 0; g < 2; g++) {
      act[g] = !(kk + 64 <= gmin[g] || kk >= gmax[g]);
      alpha[g] = 1.f;
      if (!act[g]) continue;

      // S^T = K Q^T for this group's 16 queries
      floatx4 sc[4];
      #pragma unroll
      for (int t = 0; t < 4; t++) {
        const short8 kf0 = *reinterpret_cast<const short8*>(Ks + (t * 16 + l16) * 72 + quad * 8);
        const short8 kf1 = *reinterpret_cast<const short8*>(Ks + (t * 16 + l16) * 72 + 32 + quad * 8);
        floatx4 z = {0.f,0.f,0.f,0.f};
        sc[t] = __builtin_amdgcn_mfma_f32_16x16x32_bf16(kf0, qf[g][0], z, 0, 0, 0);
        sc[t] = __builtin_amdgcn_mfma_f32_16x16x32_bf16(kf1, qf[g][1], sc[t], 0, 0, 0);
      }

      const unsigned span = (unsigned)(en[g] - st[g]);
      float vm = -1e30f;
      #pragma unroll
      for (int t = 0; t < 4; t++) {
        const int k0 = kk + t * 16 + quad * 4;
        #pragma unroll
        for (int r = 0; r < 4; r++) {
          const bool ok = (unsigned)(k0 + r - st[g]) < span;
          sc[t][r] = ok ? sc[t][r] : -1e30f;
          vm = fmaxf(vm, sc[t][r]);
        }
      }
      vm = fmaxf(vm, __shfl_xor(vm, 16));
      vm = fmaxf(vm, __shfl_xor(vm, 32));
      const float mn = fmaxf(m[g], vm);
      alpha[g] = __expf(m[g] - mn);
      m[g] = mn;

      float rs = 0.f;
      #pragma unroll
      for (int t = 0; t < 4; t++) {
        float p0 = (sc[t][0] > -1e29f) ? __expf(sc[t][0] - mn) : 0.f;
        float p1 = (sc[t][1] > -1e29f) ? __expf(sc[t][1] - mn) : 0.f;
        float p2 = (sc[t][2] > -1e29f) ? __expf(sc[t][2] - mn) : 0.f;
        float p3 = (sc[t][3] > -1e29f) ? __expf(sc[t][3] - mn) : 0.f;
        rs += (p0 + p1) + (p2 + p3);
        uint2 pk;
        pk.x = pack_bf16(p0, p1);
        pk.y = pack_bf16(p2, p3);
        *reinterpret_cast<uint2*>(&Ps[w][(g * 16 + l16) * 72 + t * 16 + quad * 4]) = pk;
      }
      rs += __shfl_xor(rs, 16);
      rs += __shfl_xor(rs, 32);
      lsum[g] = lsum[g] * alpha[g] + rs;
    }

    // read P for both groups, then shared V fragments feed both PV updates
    short8 pf[2][2];
    #pragma unroll
    for (int g = 0; g < 2; g++) {
      if (!act[g]) continue;
      pf[g][0] = *reinterpret_cast<const short8*>(&Ps[w][(g * 16 + l16) * 72 + quad * 8]);
      pf[g][1] = *reinterpret_cast<const short8*>(&Ps[w][(g * 16 + l16) * 72 + 32 + quad * 8]);
    }
    #pragma unroll
    for (int dt = 0; dt < 4; dt++) {
      const short8 vf0 = *reinterpret_cast<const short8*>(Vs + (dt * 16 + l16) * 72 + quad * 8);
      const short8 vf1 = *reinterpret_cast<const short8*>(Vs + (dt * 16 + l16) * 72 + 32 + quad * 8);
      #pragma unroll
      for (int g = 0; g < 2; g++) {
        if (!act[g]) continue;
        #pragma unroll
        for (int r = 0; r < 4; r++) acc[g][dt][r] *= alpha[g];
        acc[g][dt] = __builtin_amdgcn_mfma_f32_16x16x32_bf16(vf0, pf[g][0], acc[g][dt], 0, 0, 0);
        acc[g][dt] = __builtin_amdgcn_mfma_f32_16x16x32_bf16(vf1, pf[g][1], acc[g][dt], 0, 0, 0);
      }
    }
  }

  #pragma unroll
  for (int g = 0; g < 2; g++) {
    const float inv = (lsum[g] > 0.f) ? 1.f / lsum[g] : 0.f;
    const int qy = qbase + w * 32 + g * 16 + l16;
    unsigned short* orow = ctx + ((size_t)(b * LSEQ + qy)) * D_MODEL + h * DH;
    #pragma unroll
    for (int dt = 0; dt < 4; dt++) {
      uint2 o;
      o.x = pack_bf16(acc[g][dt][0] * inv, acc[g][dt][1] * inv);
      o.y = pack_bf16(acc[g][dt][2] * inv, acc[g][dt][3] * inv);
      *reinterpret_cast<uint2*>(orow + dt * 16 + quad * 4) = o;
    }
  }
}

// ---------------------------------------------------------------- launch
extern "C" void kernel_launch(void* const* d_in, const int* in_sizes, int n_in,
                              void* d_out, int out_size, void* d_ws, size_t ws_size,
                              hipStream_t stream) {
  const float* x      = (const float*)d_in[0];
  const int*   sid    = (const int*)d_in[1];
  const float* ln_w   = (const float*)d_in[2];
  const float* ln_b   = (const float*)d_in[3];
  const float* w_qkv  = (const float*)d_in[4];
  const float* q_ln_w = (const float*)d_in[5];
  const float* k_ln_w = (const float*)d_in[6];
  const float* w_out  = (const float*)d_in[7];
  float* out = (float*)d_out;
  char* ws = (char*)d_ws;

  constexpr size_t OFF_WQKVT = 0;                        //  6,291,456
  constexpr size_t OFF_WOUTT = 6291456;                  //  2,097,152
  constexpr size_t OFF_H     = 8388608;                  // 16,777,216
  constexpr size_t OFF_QKV   = 25165824;                 // 50,331,648 (bf16)
  constexpr size_t OFF_QT    = 75497472;                 // 16,777,216
  constexpr size_t OFF_KT    = 92274688;                 // 16,777,216
  constexpr size_t OFF_VT    = 109051904;                // 16,777,216
  constexpr size_t OFF_CTX   = 125829120;                // 16,777,216
  constexpr size_t OFF_SEGS  = 142606336;                // 32,768
  constexpr size_t OFF_SEGE  = 142639104;                // 32,768

  __hip_bfloat16* wqkvT = (__hip_bfloat16*)(ws + OFF_WQKVT);
  __hip_bfloat16* woutT = (__hip_bfloat16*)(ws + OFF_WOUTT);
  __hip_bfloat16* hbuf  = (__hip_bfloat16*)(ws + OFF_H);
  __hip_bfloat16* qkvb  = (__hip_bfloat16*)(ws + OFF_QKV);
  unsigned short* qTb   = (unsigned short*)(ws + OFF_QT);
  unsigned short* kTb   = (unsigned short*)(ws + OFF_KT);
  unsigned short* vTb   = (unsigned short*)(ws + OFF_VT);
  unsigned short* ctx   = (unsigned short*)(ws + OFF_CTX);
  int*            segst = (int*)(ws + OFF_SEGS);
  int*            segen = (int*)(ws + OFF_SEGE);

  prep_kernel<<<6176, 256, 0, stream>>>(x, ln_w, ln_b, w_qkv, w_out, sid,
                                        hbuf, wqkvT, woutT, segst, segen);
  gemm_bt<__hip_bfloat16><<<dim3(K3 / 128, NTOK / 128), 256, 0, stream>>>(
      hbuf, wqkvT, qkvb, NTOK, K3, 1024);
  ropevt_kernel<<<4096, 256, 0, stream>>>((const unsigned short*)qkvb, q_ln_w, k_ln_w,
                                          qTb, kTb, vTb);
  attn_mfma<<<dim3(LSEQ / 128, NH, BATCH), 256, 0, stream>>>(qTb, kTb, vTb, segst, segen, ctx);
  gemm_bt<float><<<dim3(D_MODEL / 128, NTOK / 128), 256, 0, stream>>>(
      (const __hip_bfloat16*)ctx, woutT, out, NTOK, D_MODEL, 1024);
}